// Round 14
// baseline (284.073 us; speedup 1.0000x reference)
//
#include <hip/hip_runtime.h>
#include <math.h>

#define NRES 4096
#define SS   128
#define A0C  5
#define ATOT 16
#define LD   256
#define PD   64
#define HD   128

typedef __attribute__((ext_vector_type(8))) short bf16x8;
typedef __attribute__((ext_vector_type(4))) float f32x4;
typedef __attribute__((ext_vector_type(4))) unsigned int u32x4;

__device__ __forceinline__ unsigned short f2bf(float x){
    unsigned int u = __builtin_bit_cast(unsigned int, x);
    unsigned int r = u + 0x7FFFu + ((u >> 16) & 1u);   // RNE to bf16
    return (unsigned short)(r >> 16);
}
__device__ __forceinline__ float gelu_f(float x){
    // x/(1+e^{-2t}), 2t = 1.59576912*(x + 0.044715 x^3)  == tanh-gelu exactly
    return x / (1.0f + __expf(-1.59576912f * x * (1.0f + 0.044715f * x * x)));
}
__device__ __forceinline__ f32x4 MFMA(bf16x8 a, bf16x8 b, f32x4 c){
    return __builtin_amdgcn_mfma_f32_16x16x32_bf16(a, b, c, 0, 0, 0);
}

// ---------------- prep: transpose+convert weights to bf16 in d_ws ----------------
// layout (ushort elements)  [identical to r5..r13 — 73728 B total]:
//   [0)      wsD   [64 n][256 k]   (w_dist^T)
//   [16384)  wsDir [64 n][64 k]    (w_dir^T, k>=48 zero)
//   [20480)  wsM1  [128 n][64 k]   (w_mlp1^T)
//   [28672)  wsM2  [64 n][128 k]   (w_mlp2^T)
__global__ void smol_prep(const float* __restrict__ wdist, const float* __restrict__ wdir,
                          const float* __restrict__ wm1,  const float* __restrict__ wm2,
                          unsigned short* __restrict__ ws)
{
    int i = blockIdx.x * 256 + threadIdx.x;
    if (i < 16384){
        int nn = i >> 8, k = i & 255;
        ws[i] = f2bf(wdist[k*64 + nn]);
    } else if (i < 20480){
        int j = i - 16384; int nn = j >> 6, k = j & 63;
        ws[i] = (k < 48) ? f2bf(wdir[k*64 + nn]) : (unsigned short)0;
    } else if (i < 28672){
        int j = i - 20480; int nn = j >> 6, k = j & 63;
        ws[i] = f2bf(wm1[k*128 + nn]);
    } else if (i < 36864){
        int j = i - 28672; int nn = j >> 7, k = j & 127;
        ws[i] = f2bf(wm2[k*64 + nn]);
    }
}

// ---------------- main fused kernel ----------------
// r14 = r13 math (bitwise) + (a) 512 threads / 8 waves, one 16-row tile per
// wave -> 4 waves/SIMD (TLP 2x), (b) T14 async-STAGE: each stage's global
// load issued into registers BEFORE the prior stage's compute; the barrier
// bracket contains only the ds_write.
struct __align__(16) SMem {
    unsigned short wbuf[64*72];     // 9216 B staged weight slice
    float  dist[128*17];            // [s][a], pad 17
    unsigned short pairT[128*72];   // bf16 [s][k<=64], stride 72
    unsigned short hidT[128*136];   // bf16 [s][k<=128], stride 136
    float  loc[LD];
    float  posall3[ATOT*3];
    float  pl[33];
    float  rot[9];
    float  ca3[3];
    float  wtypef[7*PD];
    float  basev[PD];
    float  gatevv[PD];
    float  lnsc[PD], lnof[PD];
    float  b1v[HD], b2v[PD];
    int    typef[SS];
    float  maskf[SS];
    float  red[8*PD];
    float  fin[PD];
    float  cnt;
};

// dir element: own-row coords in registers; exact IEEE divide (r11 semantics)
__device__ __forceinline__ float dirv2(const SMem& sm, float px, float py, float pz,
                                       int sl, int k){
    int kc = (k < 48) ? k : 47;
    int a = (kc * 21846) >> 16;     // kc/3
    int c = kc - 3*a;
    float pc = (c == 0) ? px : ((c == 1) ? py : pz);
    float e = (pc - sm.posall3[a*3+c]) / sm.dist[sl*17 + a];
    return (k < 48) ? e : 0.0f;
}

// r14 staging: 512 threads, one u32x4 per thread per stage.
__device__ __forceinline__ u32x4 loadStage(const unsigned short* __restrict__ src,
                                           int stride, int tid){
    int r = tid >> 3, s = (tid & 7) * 8;
    return *(const u32x4*)&src[r*stride + s];
}
// barrier (close prior wbuf reads + publish all prior LDS writes); write;
// barrier (publish slice).
__device__ __forceinline__ void pubStage(u32x4 v, unsigned short* dst, int tid){
    __syncthreads();
    int r = tid >> 3, s = (tid & 7) * 8;
    *(u32x4*)&dst[r*72 + s] = v;
    __syncthreads();
}

// RBF A-fragment for row sl, k-block kk (8 bins of atom 2kk+(g>>1)), f2bf inserts
#define RBF_FRAG(av, sl) do {                                               \
    float d_  = sm.dist[(sl)*17 + 2*kk + (g>>1)];                           \
    float dd_ = d_ * 1.33333333f;                                           \
    float z0_ = dd_ - 1.06666667f*(b0f + 0.f);                              \
    float z1_ = dd_ - 1.06666667f*(b0f + 1.f);                              \
    float z2_ = dd_ - 1.06666667f*(b0f + 2.f);                              \
    float z3_ = dd_ - 1.06666667f*(b0f + 3.f);                              \
    float z4_ = dd_ - 1.06666667f*(b0f + 4.f);                              \
    float z5_ = dd_ - 1.06666667f*(b0f + 5.f);                              \
    float z6_ = dd_ - 1.06666667f*(b0f + 6.f);                              \
    float z7_ = dd_ - 1.06666667f*(b0f + 7.f);                              \
    av[0] = (short)f2bf(__expf(-z0_*z0_));                                  \
    av[1] = (short)f2bf(__expf(-z1_*z1_));                                  \
    av[2] = (short)f2bf(__expf(-z2_*z2_));                                  \
    av[3] = (short)f2bf(__expf(-z3_*z3_));                                  \
    av[4] = (short)f2bf(__expf(-z4_*z4_));                                  \
    av[5] = (short)f2bf(__expf(-z5_*z5_));                                  \
    av[6] = (short)f2bf(__expf(-z6_*z6_));                                  \
    av[7] = (short)f2bf(__expf(-z7_*z7_));                                  \
} while(0)

__global__ __launch_bounds__(512, 2)
void smol_fused(const float* __restrict__ g_local,
                const float* __restrict__ g_pos,
                const int*   __restrict__ g_type,
                const float* __restrict__ g_spos,
                const int*   __restrict__ g_mask,
                const float* __restrict__ w_points,
                const float* __restrict__ w_local,
                const float* __restrict__ w_type,
                const float* __restrict__ ln_scale,
                const float* __restrict__ ln_offset,
                const float* __restrict__ b_mlp1,
                const float* __restrict__ b_mlp2,
                const float* __restrict__ w_gate,
                const float* __restrict__ w_out,
                const unsigned short* __restrict__ ws,
                float* __restrict__ g_out)
{
    __shared__ SMem sm;
    const int n    = blockIdx.x;
    const int tid  = threadIdx.x;
    const int wv   = tid >> 6;        // wave 0..7 : owns rows 16wv..16wv+15
    const int lane = tid & 63;
    const int cB   = lane & 15;       // A-row / B-col selector
    const int g    = lane >> 4;       // k-subgroup 0..3
    const int sl   = 16*wv + cB;      // this wave-tile's A row (s index)

    const unsigned short* wsD   = ws;
    const unsigned short* wsDir = ws + 16384;
    const unsigned short* wsM1  = ws + 20480;
    const unsigned short* wsM2  = ws + 28672;

    // ---------- stage per-n data + small weights (512 threads) ----------
    if (tid < LD) sm.loc[tid] = g_local[n*LD + tid];
    if (tid < 7*PD) sm.wtypef[tid] = w_type[tid];
    if (tid < PD){ sm.lnsc[tid] = ln_scale[tid]; sm.lnof[tid] = ln_offset[tid]; sm.b2v[tid] = b_mlp2[tid]; }
    if (tid < HD) sm.b1v[tid] = b_mlp1[tid];
    if (tid < SS){ sm.typef[tid] = g_type[n*SS + tid];
                   sm.maskf[tid] = (g_mask[n*SS + tid] != 0) ? 1.0f : 0.0f; }
    if (tid >= 128 && tid < 128 + A0C*3) sm.posall3[tid-128] = g_pos[n*A0C*3 + (tid-128)];
    __syncthreads();

    // ---------- per-n precompute (same thread roles as r13) ----------
    if (tid < 33){
        float a = 0.f;
        for (int i = 0; i < LD; ++i) a += sm.loc[i] * w_points[i*33 + tid];
        sm.pl[tid] = a;
    } else if (tid >= 64 && tid < 128){
        int p = tid - 64; float a = 0.f;
        for (int i = 0; i < LD; ++i) a += sm.loc[i] * w_local[i*PD + p];
        sm.basev[p] = a;
    } else if (tid >= 128 && tid < 192){
        int p = tid - 128; float a = 0.f;
        for (int i = 0; i < LD; ++i) a += sm.loc[i] * w_gate[i*PD + p];
        sm.gatevv[p] = gelu_f(a);
    } else if (tid == 255){
        float nx=sm.posall3[0], ny=sm.posall3[1], nz=sm.posall3[2];
        float cax=sm.posall3[3], cay=sm.posall3[4], caz=sm.posall3[5];
        float cx=sm.posall3[6], cy=sm.posall3[7], cz=sm.posall3[8];
        float v1x=cx-cax, v1y=cy-cay, v1z=cz-caz;
        float r = 1.0f/sqrtf(v1x*v1x + v1y*v1y + v1z*v1z + 1e-6f);
        float e1x=v1x*r, e1y=v1y*r, e1z=v1z*r;
        float v2x=nx-cax, v2y=ny-cay, v2z=nz-caz;
        float dp = e1x*v2x + e1y*v2y + e1z*v2z;
        float u2x=v2x-e1x*dp, u2y=v2y-e1y*dp, u2z=v2z-e1z*dp;
        r = 1.0f/sqrtf(u2x*u2x + u2y*u2y + u2z*u2z + 1e-6f);
        float e2x=u2x*r, e2y=u2y*r, e2z=u2z*r;
        float e3x=e1y*e2z-e1z*e2y, e3y=e1z*e2x-e1x*e2z, e3z=e1x*e2y-e1y*e2x;
        sm.rot[0]=e1x; sm.rot[1]=e2x; sm.rot[2]=e3x;
        sm.rot[3]=e1y; sm.rot[4]=e2y; sm.rot[5]=e3y;
        sm.rot[6]=e1z; sm.rot[7]=e2z; sm.rot[8]=e3z;
        sm.ca3[0]=cax; sm.ca3[1]=cay; sm.ca3[2]=caz;
    } else if (tid == 254){
        float c = 0.f;
        for (int s = 0; s < SS; ++s) c += sm.maskf[s];
        sm.cnt = c;
    }
    __syncthreads();
    if (tid < 33){
        int k = tid / 3, i2 = tid - k*3;
        sm.posall3[(A0C + k)*3 + i2] =
            sm.rot[i2*3+0]*sm.pl[k*3+0] + sm.rot[i2*3+1]*sm.pl[k*3+1] +
            sm.rot[i2*3+2]*sm.pl[k*3+2] + sm.ca3[i2];
    }
    __syncthreads();   // posall3 visible to all waves

    // own-row smol coords in REGISTERS (no LDS handoff)
    const float px = g_spos[(n*SS + sl)*3 + 0];
    const float py = g_spos[(n*SS + sl)*3 + 1];
    const float pz = g_spos[(n*SS + sl)*3 + 2];

    // dist for this wave's 16 rows (lane: row sl, atoms g*4..+4);
    // cross-lane reads happen only AFTER the first pubStage barrier.
    #pragma unroll
    for (int aa = 0; aa < 4; ++aa){
        int a = g*4 + aa;
        float rx = px - sm.posall3[a*3+0];
        float ry = py - sm.posall3[a*3+1];
        float rz = pz - sm.posall3[a*3+2];
        sm.dist[sl*17 + a] = sqrtf(rx*rx + ry*ry + rz*rz + 1e-6f);
    }

    const float b0f = (float)((g&1) * 8);

    // ======== fully pipelined staging: load stage h+1 before computing h ====
    u32x4 ld = loadStage(wsD, 256, tid);                 // stage 0 (wsD slice 0)

    // ---- pair GEMM: dist-RBF (K=256) ----
    f32x4 accP0 = {0.f,0.f,0.f,0.f}, accP1 = accP0, accP2 = accP0, accP3 = accP0;

    for (int h = 0; h < 4; ++h){
        pubStage(ld, sm.wbuf, tid);
        ld = (h < 3) ? loadStage(wsD + (h+1)*64, 256, tid)
                     : loadStage(wsDir, 64, tid);
        #pragma unroll
        for (int kkl = 0; kkl < 2; ++kkl){
            const int kk = h*2 + kkl;
            bf16x8 av;
            RBF_FRAG(av, sl);
            const unsigned short* bb = &sm.wbuf[cB*72 + kkl*32 + g*8];
            accP0 = MFMA(av, *(const bf16x8*)(bb +  0*72), accP0);
            accP1 = MFMA(av, *(const bf16x8*)(bb + 16*72), accP1);
            accP2 = MFMA(av, *(const bf16x8*)(bb + 32*72), accP2);
            accP3 = MFMA(av, *(const bf16x8*)(bb + 48*72), accP3);
        }
    }

    // ---- + directions @ w_dir (K=48 pad 64) ----
    pubStage(ld, sm.wbuf, tid);                          // wsDir
    ld = loadStage(wsM1, 64, tid);                       // prefetch M1a
    #pragma unroll
    for (int kk = 0; kk < 2; ++kk){
        int k0 = kk*32 + g*8;
        bf16x8 av;
        av[0] = (short)f2bf(dirv2(sm,px,py,pz,sl,k0+0));
        av[1] = (short)f2bf(dirv2(sm,px,py,pz,sl,k0+1));
        av[2] = (short)f2bf(dirv2(sm,px,py,pz,sl,k0+2));
        av[3] = (short)f2bf(dirv2(sm,px,py,pz,sl,k0+3));
        av[4] = (short)f2bf(dirv2(sm,px,py,pz,sl,k0+4));
        av[5] = (short)f2bf(dirv2(sm,px,py,pz,sl,k0+5));
        av[6] = (short)f2bf(dirv2(sm,px,py,pz,sl,k0+6));
        av[7] = (short)f2bf(dirv2(sm,px,py,pz,sl,k0+7));
        const unsigned short* bb = &sm.wbuf[cB*72 + k0];
        accP0 = MFMA(av, *(const bf16x8*)(bb +  0*72), accP0);
        accP1 = MFMA(av, *(const bf16x8*)(bb + 16*72), accP1);
        accP2 = MFMA(av, *(const bf16x8*)(bb + 32*72), accP2);
        accP3 = MFMA(av, *(const bf16x8*)(bb + 48*72), accP3);
    }

    // ---- epilogue: + base + wtype, LayerNorm, f2bf stores to pairT ----
    // (writes published by the next pubStage's leading barrier)
    #pragma unroll
    for (int r = 0; r < 4; ++r){
        int slr = 16*wv + g*4 + r;
        int ty  = sm.typef[slr];
        float v0 = accP0[r] + sm.basev[cB +  0] + sm.wtypef[ty*PD + cB +  0];
        float v1 = accP1[r] + sm.basev[cB + 16] + sm.wtypef[ty*PD + cB + 16];
        float v2 = accP2[r] + sm.basev[cB + 32] + sm.wtypef[ty*PD + cB + 32];
        float v3 = accP3[r] + sm.basev[cB + 48] + sm.wtypef[ty*PD + cB + 48];
        float ssum = v0+v1+v2+v3;
        ssum += __shfl_xor(ssum,1); ssum += __shfl_xor(ssum,2);
        ssum += __shfl_xor(ssum,4); ssum += __shfl_xor(ssum,8);
        float mu = ssum * (1.0f/64.0f);
        float d0=v0-mu, d1=v1-mu, d2=v2-mu, d3=v3-mu;
        float sq = d0*d0+d1*d1+d2*d2+d3*d3;
        sq += __shfl_xor(sq,1); sq += __shfl_xor(sq,2);
        sq += __shfl_xor(sq,4); sq += __shfl_xor(sq,8);
        float inv = 1.0f / sqrtf(sq*(1.0f/64.0f) + 1e-5f);
        unsigned short* pr = &sm.pairT[slr*72];
        pr[cB +  0] = f2bf(d0*inv*sm.lnsc[cB +  0] + sm.lnof[cB +  0]);
        pr[cB + 16] = f2bf(d1*inv*sm.lnsc[cB + 16] + sm.lnof[cB + 16]);
        pr[cB + 32] = f2bf(d2*inv*sm.lnsc[cB + 32] + sm.lnof[cB + 32]);
        pr[cB + 48] = f2bf(d3*inv*sm.lnsc[cB + 48] + sm.lnof[cB + 48]);
    }

    // ---- MLP1 (K=64, N=128) ----
    f32x4 accH0 = {0.f,0.f,0.f,0.f}, accH1 = accH0, accH2 = accH0, accH3 = accH0,
          accH4 = accH0, accH5 = accH0, accH6 = accH0, accH7 = accH0;
    pubStage(ld, sm.wbuf, tid);                          // M1a (n rows 0..63)
    ld = loadStage(wsM1 + 64*64, 64, tid);               // prefetch M1b
    #pragma unroll
    for (int kk = 0; kk < 2; ++kk){
        bf16x8 a1 = *(const bf16x8*)&sm.pairT[sl*72 + kk*32 + g*8];
        const unsigned short* bb = &sm.wbuf[cB*72 + kk*32 + g*8];
        accH0 = MFMA(a1, *(const bf16x8*)(bb + 0*16*72), accH0);
        accH1 = MFMA(a1, *(const bf16x8*)(bb + 1*16*72), accH1);
        accH2 = MFMA(a1, *(const bf16x8*)(bb + 2*16*72), accH2);
        accH3 = MFMA(a1, *(const bf16x8*)(bb + 3*16*72), accH3);
    }
    pubStage(ld, sm.wbuf, tid);                          // M1b (n rows 64..127)
    ld = loadStage(wsM2, 128, tid);                      // prefetch M2a
    #pragma unroll
    for (int kk = 0; kk < 2; ++kk){
        bf16x8 a1 = *(const bf16x8*)&sm.pairT[sl*72 + kk*32 + g*8];
        const unsigned short* bb = &sm.wbuf[cB*72 + kk*32 + g*8];
        accH4 = MFMA(a1, *(const bf16x8*)(bb + 0*16*72), accH4);
        accH5 = MFMA(a1, *(const bf16x8*)(bb + 1*16*72), accH5);
        accH6 = MFMA(a1, *(const bf16x8*)(bb + 2*16*72), accH6);
        accH7 = MFMA(a1, *(const bf16x8*)(bb + 3*16*72), accH7);
    }
    // gelu + f2bf stores to hidT (published by next pubStage barrier)
    #pragma unroll
    for (int r = 0; r < 4; ++r){
        int slr = 16*wv + g*4 + r;
        unsigned short* hr = &sm.hidT[slr*136];
        hr[cB + 0*16] = f2bf(gelu_f(accH0[r] + sm.b1v[cB + 0*16]));
        hr[cB + 1*16] = f2bf(gelu_f(accH1[r] + sm.b1v[cB + 1*16]));
        hr[cB + 2*16] = f2bf(gelu_f(accH2[r] + sm.b1v[cB + 2*16]));
        hr[cB + 3*16] = f2bf(gelu_f(accH3[r] + sm.b1v[cB + 3*16]));
        hr[cB + 4*16] = f2bf(gelu_f(accH4[r] + sm.b1v[cB + 4*16]));
        hr[cB + 5*16] = f2bf(gelu_f(accH5[r] + sm.b1v[cB + 5*16]));
        hr[cB + 6*16] = f2bf(gelu_f(accH6[r] + sm.b1v[cB + 6*16]));
        hr[cB + 7*16] = f2bf(gelu_f(accH7[r] + sm.b1v[cB + 7*16]));
    }

    // ---- MLP2 (K=128, N=64) ----
    f32x4 accO0 = {0.f,0.f,0.f,0.f}, accO1 = accO0, accO2 = accO0, accO3 = accO0;
    pubStage(ld, sm.wbuf, tid);                          // M2a (k 0..63)
    ld = loadStage(wsM2 + 64, 128, tid);                 // prefetch M2b
    #pragma unroll
    for (int kkl = 0; kkl < 2; ++kkl){
        bf16x8 a2 = *(const bf16x8*)&sm.hidT[sl*136 + kkl*32 + g*8];
        const unsigned short* bb = &sm.wbuf[cB*72 + kkl*32 + g*8];
        accO0 = MFMA(a2, *(const bf16x8*)(bb + 0*16*72), accO0);
        accO1 = MFMA(a2, *(const bf16x8*)(bb + 1*16*72), accO1);
        accO2 = MFMA(a2, *(const bf16x8*)(bb + 2*16*72), accO2);
        accO3 = MFMA(a2, *(const bf16x8*)(bb + 3*16*72), accO3);
    }
    pubStage(ld, sm.wbuf, tid);                          // M2b (k 64..127)
    #pragma unroll
    for (int kkl = 0; kkl < 2; ++kkl){
        const int kk = 2 + kkl;
        bf16x8 a2 = *(const bf16x8*)&sm.hidT[sl*136 + kk*32 + g*8];
        const unsigned short* bb = &sm.wbuf[cB*72 + kkl*32 + g*8];
        accO0 = MFMA(a2, *(const bf16x8*)(bb + 0*16*72), accO0);
        accO1 = MFMA(a2, *(const bf16x8*)(bb + 1*16*72), accO1);
        accO2 = MFMA(a2, *(const bf16x8*)(bb + 2*16*72), accO2);
        accO3 = MFMA(a2, *(const bf16x8*)(bb + 3*16*72), accO3);
    }

    float pooled0 = 0.f, pooled1 = 0.f, pooled2 = 0.f, pooled3 = 0.f;
    #pragma unroll
    for (int r = 0; r < 4; ++r){
        float m = sm.maskf[16*wv + g*4 + r];
        pooled0 += m * accO0[r];
        pooled1 += m * accO1[r];
        pooled2 += m * accO2[r];
        pooled3 += m * accO3[r];
    }

    // ---- reduce pooled: across g-groups (same col), then across 8 waves ----
    pooled0 += __shfl_xor(pooled0,16); pooled0 += __shfl_xor(pooled0,32);
    pooled1 += __shfl_xor(pooled1,16); pooled1 += __shfl_xor(pooled1,32);
    pooled2 += __shfl_xor(pooled2,16); pooled2 += __shfl_xor(pooled2,32);
    pooled3 += __shfl_xor(pooled3,16); pooled3 += __shfl_xor(pooled3,32);
    if (g == 0){
        sm.red[wv*PD + cB +  0] = pooled0;
        sm.red[wv*PD + cB + 16] = pooled1;
        sm.red[wv*PD + cB + 32] = pooled2;
        sm.red[wv*PD + cB + 48] = pooled3;
    }
    __syncthreads();
    if (tid < PD){
        float v = 0.f;
        #pragma unroll
        for (int w = 0; w < 8; ++w) v += sm.red[w*PD + tid];
        float mc = fmaxf(sm.cnt, 1.0f);
        v = (v + sm.cnt * sm.b2v[tid]) / mc;        // adds b2 exactly like ref (0 if cnt==0)
        sm.fin[tid] = sm.gatevv[tid] * v;
    }
    __syncthreads();
    if (tid < LD){
        float a = 0.f;
        #pragma unroll 4
        for (int p = 0; p < PD; ++p) a += sm.fin[p] * w_out[p*LD + tid];
        g_out[n*LD + tid] = a;
    }
}

extern "C" void kernel_launch(void* const* d_in, const int* in_sizes, int n_in,
                              void* d_out, int out_size, void* d_ws, size_t ws_size,
                              hipStream_t stream)
{
    (void)in_sizes; (void)n_in; (void)out_size; (void)ws_size;
    const float* g_local   = (const float*)d_in[0];
    const float* g_pos     = (const float*)d_in[1];
    const int*   g_type    = (const int*)  d_in[2];
    const float* g_spos    = (const float*)d_in[3];
    const int*   g_mask    = (const int*)  d_in[4];
    const float* w_points  = (const float*)d_in[5];
    const float* w_type    = (const float*)d_in[6];
    const float* w_local   = (const float*)d_in[7];
    const float* w_dir     = (const float*)d_in[8];
    const float* w_dist    = (const float*)d_in[9];
    const float* ln_scale  = (const float*)d_in[10];
    const float* ln_offset = (const float*)d_in[11];
    const float* w_mlp1    = (const float*)d_in[12];
    const float* b_mlp1    = (const float*)d_in[13];
    const float* w_mlp2    = (const float*)d_in[14];
    const float* b_mlp2    = (const float*)d_in[15];
    const float* w_gate    = (const float*)d_in[16];
    const float* w_out     = (const float*)d_in[17];

    unsigned short* ws = (unsigned short*)d_ws;   // 73728 B

    smol_prep<<<dim3(144), dim3(256), 0, stream>>>(w_dist, w_dir, w_mlp1, w_mlp2, ws);

    smol_fused<<<dim3(NRES), dim3(512), 0, stream>>>(
        g_local, g_pos, g_type, g_spos, g_mask,
        w_points, w_local, w_type, ln_scale, ln_offset,
        b_mlp1, b_mlp2, w_gate, w_out, ws, (float*)d_out);
}

// Round 15
// 165.542 us; speedup vs baseline: 1.7160x; 1.7160x over previous
//
#include <hip/hip_runtime.h>
#include <math.h>

#define NRES 4096
#define SS   128
#define A0C  5
#define ATOT 16
#define LD   256
#define PD   64
#define HD   128

typedef __attribute__((ext_vector_type(8))) short bf16x8;
typedef __attribute__((ext_vector_type(4))) float f32x4;
typedef __attribute__((ext_vector_type(4))) unsigned int u32x4;

__device__ __forceinline__ unsigned short f2bf(float x){
    unsigned int u = __builtin_bit_cast(unsigned int, x);
    unsigned int r = u + 0x7FFFu + ((u >> 16) & 1u);   // RNE to bf16
    return (unsigned short)(r >> 16);
}
__device__ __forceinline__ float gelu_f(float x){
    // x/(1+e^{-2t}), 2t = 1.59576912*(x + 0.044715 x^3)  == tanh-gelu exactly
    return x / (1.0f + __expf(-1.59576912f * x * (1.0f + 0.044715f * x * x)));
}
__device__ __forceinline__ f32x4 MFMA(bf16x8 a, bf16x8 b, f32x4 c){
    return __builtin_amdgcn_mfma_f32_16x16x32_bf16(a, b, c, 0, 0, 0);
}

// ---------------- prep: transpose+convert weights to bf16 in d_ws ----------------
// layout (ushort elements)  [identical to r5..r13 — 73728 B total]:
//   [0)      wsD   [64 n][256 k]   (w_dist^T)
//   [16384)  wsDir [64 n][64 k]    (w_dir^T, k>=48 zero)
//   [20480)  wsM1  [128 n][64 k]   (w_mlp1^T)
//   [28672)  wsM2  [64 n][128 k]   (w_mlp2^T)
__global__ void smol_prep(const float* __restrict__ wdist, const float* __restrict__ wdir,
                          const float* __restrict__ wm1,  const float* __restrict__ wm2,
                          unsigned short* __restrict__ ws)
{
    int i = blockIdx.x * 256 + threadIdx.x;
    if (i < 16384){
        int nn = i >> 8, k = i & 255;
        ws[i] = f2bf(wdist[k*64 + nn]);
    } else if (i < 20480){
        int j = i - 16384; int nn = j >> 6, k = j & 63;
        ws[i] = (k < 48) ? f2bf(wdir[k*64 + nn]) : (unsigned short)0;
    } else if (i < 28672){
        int j = i - 20480; int nn = j >> 6, k = j & 63;
        ws[i] = f2bf(wm1[k*128 + nn]);
    } else if (i < 36864){
        int j = i - 28672; int nn = j >> 7, k = j & 127;
        ws[i] = f2bf(wm2[k*64 + nn]);
    }
}

// ---------------- main fused kernel ----------------
// r15 = r13 (4 waves x 2 tiles, the fast config) with LDS cut to ~53.4 KB
// -> 3 blocks/CU (12 waves/CU, +50% TLP):
//   (a) MLP1/MLP2 interleaved in k-halves: hidden cols 0..63 computed then
//       immediately consumed as MLP2 k=0..63, then cols 64..127 / k=64..127.
//       Same MFMA order & values as r13 -> bit-identical output.
//   (b) hidT shrinks to [128][72] (one half at a time), UNIONed with dist
//       (dist dead before first hidT write; separated by stageW barrier).
struct __align__(16) SMem {
    unsigned short wbuf[64*72];     // 9216 B staged weight slice
    union {
        float  dist[128*17];        // 8704 B; live until dir phase
        unsigned short hidT[128*72];// 18432 B; live in MLP1/MLP2 (after barrier)
    };
    unsigned short pairT[128*72];   // bf16 [s][k<=64], stride 72
    float  loc[LD];
    float  posall3[ATOT*3];
    float  pl[33];
    float  rot[9];
    float  ca3[3];
    float  wtypef[7*PD];
    float  basev[PD];
    float  gatevv[PD];
    float  lnsc[PD], lnof[PD];
    float  b1v[HD], b2v[PD];
    int    typef[SS];
    float  maskf[SS];
    float  red[4*PD];
    float  fin[PD];
    float  cnt;
};

// dir element: own-row coords in registers; exact IEEE divide (r11 semantics)
__device__ __forceinline__ float dirv2(const SMem& sm, float px, float py, float pz,
                                       int sl, int k){
    int kc = (k < 48) ? k : 47;
    int a = (kc * 21846) >> 16;     // kc/3
    int c = kc - 3*a;
    float pc = (c == 0) ? px : ((c == 1) ? py : pz);
    float e = (pc - sm.posall3[a*3+c]) / sm.dist[sl*17 + a];
    return (k < 48) ? e : 0.0f;
}

// stage a [64 rows][64 k] slice from global (row stride `stride` ushorts)
// into wbuf (row stride 72). Leading barrier closes prior wbuf reads AND
// publishes all waves' prior LDS writes; trailing barrier publishes the slice.
__device__ __forceinline__ void stageW(const unsigned short* __restrict__ src, int stride,
                                       unsigned short* dst, int tid){
    __syncthreads();
    int r = tid >> 3, s = (tid & 7) * 8;
    *(u32x4*)&dst[r*72 + s]      = *(const u32x4*)&src[r*stride + s];
    *(u32x4*)&dst[(r+32)*72 + s] = *(const u32x4*)&src[(r+32)*stride + s];
    __syncthreads();
}

// RBF A-fragment for row sl, k-block kk (8 bins of atom 2kk+(g>>1)), f2bf inserts
#define RBF_FRAG(av, sl) do {                                               \
    float d_  = sm.dist[(sl)*17 + 2*kk + (g>>1)];                           \
    float dd_ = d_ * 1.33333333f;                                           \
    float z0_ = dd_ - 1.06666667f*(b0f + 0.f);                              \
    float z1_ = dd_ - 1.06666667f*(b0f + 1.f);                              \
    float z2_ = dd_ - 1.06666667f*(b0f + 2.f);                              \
    float z3_ = dd_ - 1.06666667f*(b0f + 3.f);                              \
    float z4_ = dd_ - 1.06666667f*(b0f + 4.f);                              \
    float z5_ = dd_ - 1.06666667f*(b0f + 5.f);                              \
    float z6_ = dd_ - 1.06666667f*(b0f + 6.f);                              \
    float z7_ = dd_ - 1.06666667f*(b0f + 7.f);                              \
    av[0] = (short)f2bf(__expf(-z0_*z0_));                                  \
    av[1] = (short)f2bf(__expf(-z1_*z1_));                                  \
    av[2] = (short)f2bf(__expf(-z2_*z2_));                                  \
    av[3] = (short)f2bf(__expf(-z3_*z3_));                                  \
    av[4] = (short)f2bf(__expf(-z4_*z4_));                                  \
    av[5] = (short)f2bf(__expf(-z5_*z5_));                                  \
    av[6] = (short)f2bf(__expf(-z6_*z6_));                                  \
    av[7] = (short)f2bf(__expf(-z7_*z7_));                                  \
} while(0)

__global__ __launch_bounds__(256, 3)
void smol_fused(const float* __restrict__ g_local,
                const float* __restrict__ g_pos,
                const int*   __restrict__ g_type,
                const float* __restrict__ g_spos,
                const int*   __restrict__ g_mask,
                const float* __restrict__ w_points,
                const float* __restrict__ w_local,
                const float* __restrict__ w_type,
                const float* __restrict__ ln_scale,
                const float* __restrict__ ln_offset,
                const float* __restrict__ b_mlp1,
                const float* __restrict__ b_mlp2,
                const float* __restrict__ w_gate,
                const float* __restrict__ w_out,
                const unsigned short* __restrict__ ws,
                float* __restrict__ g_out)
{
    __shared__ SMem sm;
    const int n    = blockIdx.x;
    const int tid  = threadIdx.x;
    const int wv   = tid >> 6;        // wave 0..3 : owns rows 32wv..32wv+31
    const int lane = tid & 63;
    const int cB   = lane & 15;       // A-row / B-col selector
    const int g    = lane >> 4;       // k-subgroup 0..3
    const int sl0  = 32*wv + cB;      // tile-0 A row (s index)
    const int sl1  = sl0 + 16;        // tile-1 A row

    const unsigned short* wsD   = ws;
    const unsigned short* wsDir = ws + 16384;
    const unsigned short* wsM1  = ws + 20480;
    const unsigned short* wsM2  = ws + 28672;

    // ---------- stage per-n data + small weights ----------
    sm.loc[tid] = g_local[n*LD + tid];
    sm.wtypef[tid] = w_type[tid];
    if (tid < 7*PD - 256) sm.wtypef[256 + tid] = w_type[256 + tid];
    if (tid < PD){ sm.lnsc[tid] = ln_scale[tid]; sm.lnof[tid] = ln_offset[tid]; sm.b2v[tid] = b_mlp2[tid]; }
    if (tid < HD) sm.b1v[tid] = b_mlp1[tid];
    if (tid < SS){ sm.typef[tid] = g_type[n*SS + tid];
                   sm.maskf[tid] = (g_mask[n*SS + tid] != 0) ? 1.0f : 0.0f; }
    if (tid >= 128 && tid < 128 + A0C*3) sm.posall3[tid-128] = g_pos[n*A0C*3 + (tid-128)];
    __syncthreads();

    // ---------- per-n precompute ----------
    if (tid < 33){
        float a = 0.f;
        for (int i = 0; i < LD; ++i) a += sm.loc[i] * w_points[i*33 + tid];
        sm.pl[tid] = a;
    } else if (tid >= 64 && tid < 128){
        int p = tid - 64; float a = 0.f;
        for (int i = 0; i < LD; ++i) a += sm.loc[i] * w_local[i*PD + p];
        sm.basev[p] = a;
    } else if (tid >= 128 && tid < 192){
        int p = tid - 128; float a = 0.f;
        for (int i = 0; i < LD; ++i) a += sm.loc[i] * w_gate[i*PD + p];
        sm.gatevv[p] = gelu_f(a);
    } else if (tid == 255){
        float nx=sm.posall3[0], ny=sm.posall3[1], nz=sm.posall3[2];
        float cax=sm.posall3[3], cay=sm.posall3[4], caz=sm.posall3[5];
        float cx=sm.posall3[6], cy=sm.posall3[7], cz=sm.posall3[8];
        float v1x=cx-cax, v1y=cy-cay, v1z=cz-caz;
        float r = 1.0f/sqrtf(v1x*v1x + v1y*v1y + v1z*v1z + 1e-6f);
        float e1x=v1x*r, e1y=v1y*r, e1z=v1z*r;
        float v2x=nx-cax, v2y=ny-cay, v2z=nz-caz;
        float dp = e1x*v2x + e1y*v2y + e1z*v2z;
        float u2x=v2x-e1x*dp, u2y=v2y-e1y*dp, u2z=v2z-e1z*dp;
        r = 1.0f/sqrtf(u2x*u2x + u2y*u2y + u2z*u2z + 1e-6f);
        float e2x=u2x*r, e2y=u2y*r, e2z=u2z*r;
        float e3x=e1y*e2z-e1z*e2y, e3y=e1z*e2x-e1x*e2z, e3z=e1x*e2y-e1y*e2x;
        sm.rot[0]=e1x; sm.rot[1]=e2x; sm.rot[2]=e3x;
        sm.rot[3]=e1y; sm.rot[4]=e2y; sm.rot[5]=e3y;
        sm.rot[6]=e1z; sm.rot[7]=e2z; sm.rot[8]=e3z;
        sm.ca3[0]=cax; sm.ca3[1]=cay; sm.ca3[2]=caz;
    } else if (tid == 254){
        float c = 0.f;
        for (int s = 0; s < SS; ++s) c += sm.maskf[s];
        sm.cnt = c;
    }
    __syncthreads();
    if (tid < 33){
        int k = tid / 3, i2 = tid - k*3;
        sm.posall3[(A0C + k)*3 + i2] =
            sm.rot[i2*3+0]*sm.pl[k*3+0] + sm.rot[i2*3+1]*sm.pl[k*3+1] +
            sm.rot[i2*3+2]*sm.pl[k*3+2] + sm.ca3[i2];
    }
    __syncthreads();   // posall3 visible to all waves

    // own-row smol coords in REGISTERS (no LDS handoff)
    const float px0 = g_spos[(n*SS + sl0)*3 + 0];
    const float py0 = g_spos[(n*SS + sl0)*3 + 1];
    const float pz0 = g_spos[(n*SS + sl0)*3 + 2];
    const float px1 = g_spos[(n*SS + sl1)*3 + 0];
    const float py1 = g_spos[(n*SS + sl1)*3 + 1];
    const float pz1 = g_spos[(n*SS + sl1)*3 + 2];

    // dist for this wave's 32 rows (lane: rows sl0/sl1, atoms g*4..+4);
    // cross-lane reads happen only AFTER the next stageW barrier.
    #pragma unroll
    for (int aa = 0; aa < 4; ++aa){
        int a = g*4 + aa;
        float ax = sm.posall3[a*3+0], ay = sm.posall3[a*3+1], az = sm.posall3[a*3+2];
        float rx0 = px0-ax, ry0 = py0-ay, rz0 = pz0-az;
        sm.dist[sl0*17 + a] = sqrtf(rx0*rx0 + ry0*ry0 + rz0*rz0 + 1e-6f);
        float rx1 = px1-ax, ry1 = py1-ay, rz1 = pz1-az;
        sm.dist[sl1*17 + a] = sqrtf(rx1*rx1 + ry1*ry1 + rz1*rz1 + 1e-6f);
    }

    const float b0f = (float)((g&1) * 8);

    // ---- pair GEMM: dist-RBF (K=256), B staged once in 4 k-slices ----
    f32x4 accP0 = {0.f,0.f,0.f,0.f}, accP1 = accP0, accP2 = accP0, accP3 = accP0;  // tile 0
    f32x4 accQ0 = accP0, accQ1 = accP0, accQ2 = accP0, accQ3 = accP0;              // tile 1

    for (int h = 0; h < 4; ++h){
        stageW(wsD + h*64, 256, sm.wbuf, tid);
        #pragma unroll
        for (int kkl = 0; kkl < 2; ++kkl){
            const int kk = h*2 + kkl;
            bf16x8 av0, av1;
            RBF_FRAG(av0, sl0);
            RBF_FRAG(av1, sl1);
            const unsigned short* bb = &sm.wbuf[cB*72 + kkl*32 + g*8];
            bf16x8 B0 = *(const bf16x8*)(bb +  0*72);
            bf16x8 B1 = *(const bf16x8*)(bb + 16*72);
            bf16x8 B2 = *(const bf16x8*)(bb + 32*72);
            bf16x8 B3 = *(const bf16x8*)(bb + 48*72);
            accP0 = MFMA(av0, B0, accP0);  accQ0 = MFMA(av1, B0, accQ0);
            accP1 = MFMA(av0, B1, accP1);  accQ1 = MFMA(av1, B1, accQ1);
            accP2 = MFMA(av0, B2, accP2);  accQ2 = MFMA(av1, B2, accQ2);
            accP3 = MFMA(av0, B3, accP3);  accQ3 = MFMA(av1, B3, accQ3);
        }
    }

    // ---- + directions @ w_dir (K=48 pad 64), one staged slice ----
    stageW(wsDir, 64, sm.wbuf, tid);
    #pragma unroll
    for (int kk = 0; kk < 2; ++kk){
        int k0 = kk*32 + g*8;
        bf16x8 av0, av1;
        av0[0] = (short)f2bf(dirv2(sm,px0,py0,pz0,sl0,k0+0));
        av0[1] = (short)f2bf(dirv2(sm,px0,py0,pz0,sl0,k0+1));
        av0[2] = (short)f2bf(dirv2(sm,px0,py0,pz0,sl0,k0+2));
        av0[3] = (short)f2bf(dirv2(sm,px0,py0,pz0,sl0,k0+3));
        av0[4] = (short)f2bf(dirv2(sm,px0,py0,pz0,sl0,k0+4));
        av0[5] = (short)f2bf(dirv2(sm,px0,py0,pz0,sl0,k0+5));
        av0[6] = (short)f2bf(dirv2(sm,px0,py0,pz0,sl0,k0+6));
        av0[7] = (short)f2bf(dirv2(sm,px0,py0,pz0,sl0,k0+7));
        av1[0] = (short)f2bf(dirv2(sm,px1,py1,pz1,sl1,k0+0));
        av1[1] = (short)f2bf(dirv2(sm,px1,py1,pz1,sl1,k0+1));
        av1[2] = (short)f2bf(dirv2(sm,px1,py1,pz1,sl1,k0+2));
        av1[3] = (short)f2bf(dirv2(sm,px1,py1,pz1,sl1,k0+3));
        av1[4] = (short)f2bf(dirv2(sm,px1,py1,pz1,sl1,k0+4));
        av1[5] = (short)f2bf(dirv2(sm,px1,py1,pz1,sl1,k0+5));
        av1[6] = (short)f2bf(dirv2(sm,px1,py1,pz1,sl1,k0+6));
        av1[7] = (short)f2bf(dirv2(sm,px1,py1,pz1,sl1,k0+7));
        const unsigned short* bb = &sm.wbuf[cB*72 + k0];
        bf16x8 B0 = *(const bf16x8*)(bb +  0*72);
        bf16x8 B1 = *(const bf16x8*)(bb + 16*72);
        bf16x8 B2 = *(const bf16x8*)(bb + 32*72);
        bf16x8 B3 = *(const bf16x8*)(bb + 48*72);
        accP0 = MFMA(av0, B0, accP0);  accQ0 = MFMA(av1, B0, accQ0);
        accP1 = MFMA(av0, B1, accP1);  accQ1 = MFMA(av1, B1, accQ1);
        accP2 = MFMA(av0, B2, accP2);  accQ2 = MFMA(av1, B2, accQ2);
        accP3 = MFMA(av0, B3, accP3);  accQ3 = MFMA(av1, B3, accQ3);
    }

    // ---- epilogue: + base + wtype, LayerNorm, f2bf stores to pairT ----
    // (last dist reads were above; hidT first written only after the next
    //  stageW's leading barrier -> dist/hidT union is safe)
    #pragma unroll
    for (int t = 0; t < 2; ++t){
        #pragma unroll
        for (int r = 0; r < 4; ++r){
            int slr = 32*wv + 16*t + g*4 + r;
            int ty  = sm.typef[slr];
            float a0 = (t==0 ? accP0[r] : accQ0[r]);
            float a1 = (t==0 ? accP1[r] : accQ1[r]);
            float a2 = (t==0 ? accP2[r] : accQ2[r]);
            float a3 = (t==0 ? accP3[r] : accQ3[r]);
            float v0 = a0 + sm.basev[cB +  0] + sm.wtypef[ty*PD + cB +  0];
            float v1 = a1 + sm.basev[cB + 16] + sm.wtypef[ty*PD + cB + 16];
            float v2 = a2 + sm.basev[cB + 32] + sm.wtypef[ty*PD + cB + 32];
            float v3 = a3 + sm.basev[cB + 48] + sm.wtypef[ty*PD + cB + 48];
            float ssum = v0+v1+v2+v3;
            ssum += __shfl_xor(ssum,1); ssum += __shfl_xor(ssum,2);
            ssum += __shfl_xor(ssum,4); ssum += __shfl_xor(ssum,8);
            float mu = ssum * (1.0f/64.0f);
            float d0=v0-mu, d1=v1-mu, d2=v2-mu, d3=v3-mu;
            float sq = d0*d0+d1*d1+d2*d2+d3*d3;
            sq += __shfl_xor(sq,1); sq += __shfl_xor(sq,2);
            sq += __shfl_xor(sq,4); sq += __shfl_xor(sq,8);
            float inv = 1.0f / sqrtf(sq*(1.0f/64.0f) + 1e-5f);
            unsigned short* pr = &sm.pairT[slr*72];
            pr[cB +  0] = f2bf(d0*inv*sm.lnsc[cB +  0] + sm.lnof[cB +  0]);
            pr[cB + 16] = f2bf(d1*inv*sm.lnsc[cB + 16] + sm.lnof[cB + 16]);
            pr[cB + 32] = f2bf(d2*inv*sm.lnsc[cB + 32] + sm.lnof[cB + 32]);
            pr[cB + 48] = f2bf(d3*inv*sm.lnsc[cB + 48] + sm.lnof[cB + 48]);
        }
    }

    // ==== MLP1/MLP2 interleaved in k-halves (same MFMA order/values as r13) ====
    f32x4 accO0 = {0.f,0.f,0.f,0.f}, accO1 = accO0, accO2 = accO0, accO3 = accO0;  // tile 0
    f32x4 accN0 = accO0, accN1 = accO0, accN2 = accO0, accN3 = accO0;              // tile 1

    // ---- MLP1 half a (hidden cols 0..63) ----
    f32x4 accH0 = {0.f,0.f,0.f,0.f}, accH1 = accH0, accH2 = accH0, accH3 = accH0;  // tile 0
    f32x4 accI0 = accH0, accI1 = accH0, accI2 = accH0, accI3 = accH0;              // tile 1
    stageW(wsM1, 64, sm.wbuf, tid);     // leading barrier publishes pairT + retires dist
    #pragma unroll
    for (int kk = 0; kk < 2; ++kk){
        bf16x8 a0 = *(const bf16x8*)&sm.pairT[sl0*72 + kk*32 + g*8];
        bf16x8 a1 = *(const bf16x8*)&sm.pairT[sl1*72 + kk*32 + g*8];
        const unsigned short* bb = &sm.wbuf[cB*72 + kk*32 + g*8];
        bf16x8 B0 = *(const bf16x8*)(bb + 0*16*72);
        bf16x8 B1 = *(const bf16x8*)(bb + 1*16*72);
        bf16x8 B2 = *(const bf16x8*)(bb + 2*16*72);
        bf16x8 B3 = *(const bf16x8*)(bb + 3*16*72);
        accH0 = MFMA(a0, B0, accH0);  accI0 = MFMA(a1, B0, accI0);
        accH1 = MFMA(a0, B1, accH1);  accI1 = MFMA(a1, B1, accI1);
        accH2 = MFMA(a0, B2, accH2);  accI2 = MFMA(a1, B2, accI2);
        accH3 = MFMA(a0, B3, accH3);  accI3 = MFMA(a1, B3, accI3);
    }
    // gelu + f2bf stores: hidden cols 0..63 -> hidT local cols 0..63 (wave-own rows)
    #pragma unroll
    for (int r = 0; r < 4; ++r){
        int slr0 = 32*wv + g*4 + r;
        unsigned short* hr0 = &sm.hidT[slr0*72];
        hr0[cB + 0*16] = f2bf(gelu_f(accH0[r] + sm.b1v[cB + 0*16]));
        hr0[cB + 1*16] = f2bf(gelu_f(accH1[r] + sm.b1v[cB + 1*16]));
        hr0[cB + 2*16] = f2bf(gelu_f(accH2[r] + sm.b1v[cB + 2*16]));
        hr0[cB + 3*16] = f2bf(gelu_f(accH3[r] + sm.b1v[cB + 3*16]));
        unsigned short* hr1 = &sm.hidT[(slr0+16)*72];
        hr1[cB + 0*16] = f2bf(gelu_f(accI0[r] + sm.b1v[cB + 0*16]));
        hr1[cB + 1*16] = f2bf(gelu_f(accI1[r] + sm.b1v[cB + 1*16]));
        hr1[cB + 2*16] = f2bf(gelu_f(accI2[r] + sm.b1v[cB + 2*16]));
        hr1[cB + 3*16] = f2bf(gelu_f(accI3[r] + sm.b1v[cB + 3*16]));
    }

    // ---- MLP2 k-half 0 (k = 0..63) ----
    stageW(wsM2, 128, sm.wbuf, tid);    // leading barrier publishes hidT half a
    #pragma unroll
    for (int kkl = 0; kkl < 2; ++kkl){
        bf16x8 a0 = *(const bf16x8*)&sm.hidT[sl0*72 + kkl*32 + g*8];
        bf16x8 a1 = *(const bf16x8*)&sm.hidT[sl1*72 + kkl*32 + g*8];
        const unsigned short* bb = &sm.wbuf[cB*72 + kkl*32 + g*8];
        bf16x8 B0 = *(const bf16x8*)(bb + 0*16*72);
        bf16x8 B1 = *(const bf16x8*)(bb + 1*16*72);
        bf16x8 B2 = *(const bf16x8*)(bb + 2*16*72);
        bf16x8 B3 = *(const bf16x8*)(bb + 3*16*72);
        accO0 = MFMA(a0, B0, accO0);  accN0 = MFMA(a1, B0, accN0);
        accO1 = MFMA(a0, B1, accO1);  accN1 = MFMA(a1, B1, accN1);
        accO2 = MFMA(a0, B2, accO2);  accN2 = MFMA(a1, B2, accN2);
        accO3 = MFMA(a0, B3, accO3);  accN3 = MFMA(a1, B3, accN3);
    }

    // ---- MLP1 half b (hidden cols 64..127) ----
    f32x4 accH4 = {0.f,0.f,0.f,0.f}, accH5 = accH4, accH6 = accH4, accH7 = accH4;
    f32x4 accI4 = accH4, accI5 = accH4, accI6 = accH4, accI7 = accH4;
    stageW(wsM1 + 64*64, 64, sm.wbuf, tid);   // leading barrier retires hidT-half-a reads
    #pragma unroll
    for (int kk = 0; kk < 2; ++kk){
        bf16x8 a0 = *(const bf16x8*)&sm.pairT[sl0*72 + kk*32 + g*8];
        bf16x8 a1 = *(const bf16x8*)&sm.pairT[sl1*72 + kk*32 + g*8];
        const unsigned short* bb = &sm.wbuf[cB*72 + kk*32 + g*8];
        bf16x8 B0 = *(const bf16x8*)(bb + 0*16*72);
        bf16x8 B1 = *(const bf16x8*)(bb + 1*16*72);
        bf16x8 B2 = *(const bf16x8*)(bb + 2*16*72);
        bf16x8 B3 = *(const bf16x8*)(bb + 3*16*72);
        accH4 = MFMA(a0, B0, accH4);  accI4 = MFMA(a1, B0, accI4);
        accH5 = MFMA(a0, B1, accH5);  accI5 = MFMA(a1, B1, accI5);
        accH6 = MFMA(a0, B2, accH6);  accI6 = MFMA(a1, B2, accI6);
        accH7 = MFMA(a0, B3, accH7);  accI7 = MFMA(a1, B3, accI7);
    }
    // gelu + f2bf stores: hidden cols 64..127 -> hidT local cols 0..63
    #pragma unroll
    for (int r = 0; r < 4; ++r){
        int slr0 = 32*wv + g*4 + r;
        unsigned short* hr0 = &sm.hidT[slr0*72];
        hr0[cB + 0*16] = f2bf(gelu_f(accH4[r] + sm.b1v[cB + 4*16]));
        hr0[cB + 1*16] = f2bf(gelu_f(accH5[r] + sm.b1v[cB + 5*16]));
        hr0[cB + 2*16] = f2bf(gelu_f(accH6[r] + sm.b1v[cB + 6*16]));
        hr0[cB + 3*16] = f2bf(gelu_f(accH7[r] + sm.b1v[cB + 7*16]));
        unsigned short* hr1 = &sm.hidT[(slr0+16)*72];
        hr1[cB + 0*16] = f2bf(gelu_f(accI4[r] + sm.b1v[cB + 4*16]));
        hr1[cB + 1*16] = f2bf(gelu_f(accI5[r] + sm.b1v[cB + 5*16]));
        hr1[cB + 2*16] = f2bf(gelu_f(accI6[r] + sm.b1v[cB + 6*16]));
        hr1[cB + 3*16] = f2bf(gelu_f(accI7[r] + sm.b1v[cB + 7*16]));
    }

    // ---- MLP2 k-half 1 (k = 64..127) ----
    stageW(wsM2 + 64, 128, sm.wbuf, tid);     // leading barrier publishes hidT half b
    #pragma unroll
    for (int kkl = 0; kkl < 2; ++kkl){
        bf16x8 a0 = *(const bf16x8*)&sm.hidT[sl0*72 + kkl*32 + g*8];
        bf16x8 a1 = *(const bf16x8*)&sm.hidT[sl1*72 + kkl*32 + g*8];
        const unsigned short* bb = &sm.wbuf[cB*72 + kkl*32 + g*8];
        bf16x8 B0 = *(const bf16x8*)(bb + 0*16*72);
        bf16x8 B1 = *(const bf16x8*)(bb + 1*16*72);
        bf16x8 B2 = *(const bf16x8*)(bb + 2*16*72);
        bf16x8 B3 = *(const bf16x8*)(bb + 3*16*72);
        accO0 = MFMA(a0, B0, accO0);  accN0 = MFMA(a1, B0, accN0);
        accO1 = MFMA(a0, B1, accO1);  accN1 = MFMA(a1, B1, accN1);
        accO2 = MFMA(a0, B2, accO2);  accN2 = MFMA(a1, B2, accN2);
        accO3 = MFMA(a0, B3, accO3);  accN3 = MFMA(a1, B3, accN3);
    }

    float pooled0 = 0.f, pooled1 = 0.f, pooled2 = 0.f, pooled3 = 0.f;
    #pragma unroll
    for (int r = 0; r < 4; ++r){
        float m0f = sm.maskf[32*wv + g*4 + r];
        float m1f = sm.maskf[32*wv + 16 + g*4 + r];
        pooled0 += m0f * accO0[r] + m1f * accN0[r];
        pooled1 += m0f * accO1[r] + m1f * accN1[r];
        pooled2 += m0f * accO2[r] + m1f * accN2[r];
        pooled3 += m0f * accO3[r] + m1f * accN3[r];
    }

    // ---- reduce pooled: across g-groups (same col), then across waves ----
    pooled0 += __shfl_xor(pooled0,16); pooled0 += __shfl_xor(pooled0,32);
    pooled1 += __shfl_xor(pooled1,16); pooled1 += __shfl_xor(pooled1,32);
    pooled2 += __shfl_xor(pooled2,16); pooled2 += __shfl_xor(pooled2,32);
    pooled3 += __shfl_xor(pooled3,16); pooled3 += __shfl_xor(pooled3,32);
    if (g == 0){
        sm.red[wv*PD + cB +  0] = pooled0;
        sm.red[wv*PD + cB + 16] = pooled1;
        sm.red[wv*PD + cB + 32] = pooled2;
        sm.red[wv*PD + cB + 48] = pooled3;
    }
    __syncthreads();
    if (tid < PD){
        float v = sm.red[tid] + sm.red[PD + tid] + sm.red[2*PD + tid] + sm.red[3*PD + tid];
        float mc = fmaxf(sm.cnt, 1.0f);
        v = (v + sm.cnt * sm.b2v[tid]) / mc;        // adds b2 exactly like ref (0 if cnt==0)
        sm.fin[tid] = sm.gatevv[tid] * v;
    }
    __syncthreads();
    {
        float a = 0.f;
        #pragma unroll 4
        for (int p = 0; p < PD; ++p) a += sm.fin[p] * w_out[p*LD + tid];
        g_out[n*LD + tid] = a;
    }
}

extern "C" void kernel_launch(void* const* d_in, const int* in_sizes, int n_in,
                              void* d_out, int out_size, void* d_ws, size_t ws_size,
                              hipStream_t stream)
{
    (void)in_sizes; (void)n_in; (void)out_size; (void)ws_size;
    const float* g_local   = (const float*)d_in[0];
    const float* g_pos     = (const float*)d_in[1];
    const int*   g_type    = (const int*)  d_in[2];
    const float* g_spos    = (const float*)d_in[3];
    const int*   g_mask    = (const int*)  d_in[4];
    const float* w_points  = (const float*)d_in[5];
    const float* w_type    = (const float*)d_in[6];
    const float* w_local   = (const float*)d_in[7];
    const float* w_dir     = (const float*)d_in[8];
    const float* w_dist    = (const float*)d_in[9];
    const float* ln_scale  = (const float*)d_in[10];
    const float* ln_offset = (const float*)d_in[11];
    const float* w_mlp1    = (const float*)d_in[12];
    const float* b_mlp1    = (const float*)d_in[13];
    const float* w_mlp2    = (const float*)d_in[14];
    const float* b_mlp2    = (const float*)d_in[15];
    const float* w_gate    = (const float*)d_in[16];
    const float* w_out     = (const float*)d_in[17];

    unsigned short* ws = (unsigned short*)d_ws;   // 73728 B

    smol_prep<<<dim3(144), dim3(256), 0, stream>>>(w_dist, w_dir, w_mlp1, w_mlp2, ws);

    smol_fused<<<dim3(NRES), dim3(256), 0, stream>>>(
        g_local, g_pos, g_type, g_spos, g_mask,
        w_points, w_local, w_type, ln_scale, ln_offset,
        b_mlp1, b_mlp2, w_gate, w_out, ws, (float*)d_out);
}

// Round 16
// 142.269 us; speedup vs baseline: 1.9967x; 1.1636x over previous
//
#include <hip/hip_runtime.h>
#include <math.h>

#define NRES 4096
#define SS   128
#define A0C  5
#define ATOT 16
#define LD   256
#define PD   64
#define HD   128

typedef __attribute__((ext_vector_type(8))) short bf16x8;
typedef __attribute__((ext_vector_type(4))) float f32x4;
typedef __attribute__((ext_vector_type(4))) unsigned int u32x4;

__device__ __forceinline__ unsigned short f2bf(float x){
    unsigned int u = __builtin_bit_cast(unsigned int, x);
    unsigned int r = u + 0x7FFFu + ((u >> 16) & 1u);   // RNE to bf16 (prep only)
    return (unsigned short)(r >> 16);
}
// r16: cheap conversions. Round-half-up (+0x8000) differs from RNE only at
// exact ties -> statistically identical accuracy, half the ops.
__device__ __forceinline__ unsigned short f2bfhu(float x){
    return (unsigned short)((__builtin_bit_cast(unsigned int, x) + 0x8000u) >> 16);
}
// pack two f32 -> one u32 of 2 bf16 (lo,hi) in 3 VALU ops via v_perm_b32.
__device__ __forceinline__ unsigned int pk2bf(float lo, float hi){
    unsigned int a = __builtin_bit_cast(unsigned int, lo) + 0x8000u;
    unsigned int b = __builtin_bit_cast(unsigned int, hi) + 0x8000u;
    return __builtin_amdgcn_perm(b, a, 0x07060302u);   // bytes: a.b2,a.b3,b.b2,b.b3
}
__device__ __forceinline__ float gelu_f(float x){
    // x * rcp(1+e^{-2t}) — rcpf is ~1ULP, output goes to bf16 anyway
    float e = __expf(-1.59576912f * x * (1.0f + 0.044715f * x * x));
    return x * __builtin_amdgcn_rcpf(1.0f + e);
}
__device__ __forceinline__ f32x4 MFMA(bf16x8 a, bf16x8 b, f32x4 c){
    return __builtin_amdgcn_mfma_f32_16x16x32_bf16(a, b, c, 0, 0, 0);
}

// ---------------- prep: transpose+convert weights to bf16 in d_ws ----------------
// layout (ushort elements)  [identical to r5..r15 — 73728 B total]:
//   [0)      wsD   [64 n][256 k]   (w_dist^T)
//   [16384)  wsDir [64 n][64 k]    (w_dir^T, k>=48 zero)
//   [20480)  wsM1  [128 n][64 k]   (w_mlp1^T)
//   [28672)  wsM2  [64 n][128 k]   (w_mlp2^T)
__global__ void smol_prep(const float* __restrict__ wdist, const float* __restrict__ wdir,
                          const float* __restrict__ wm1,  const float* __restrict__ wm2,
                          unsigned short* __restrict__ ws)
{
    int i = blockIdx.x * 256 + threadIdx.x;
    if (i < 16384){
        int nn = i >> 8, k = i & 255;
        ws[i] = f2bf(wdist[k*64 + nn]);
    } else if (i < 20480){
        int j = i - 16384; int nn = j >> 6, k = j & 63;
        ws[i] = (k < 48) ? f2bf(wdir[k*64 + nn]) : (unsigned short)0;
    } else if (i < 28672){
        int j = i - 20480; int nn = j >> 6, k = j & 63;
        ws[i] = f2bf(wm1[k*128 + nn]);
    } else if (i < 36864){
        int j = i - 28672; int nn = j >> 7, k = j & 127;
        ws[i] = f2bf(wm2[k*64 + nn]);
    }
}

// ---------------- main fused kernel ----------------
// r16 = r15 structure EXACTLY (4 waves x 2 tiles, k-half MLP interleave,
// dist/hidT union, 3 blocks/CU) + VALU diet:
//  - RBF: exp2 with sigma+log2e folded into the argument (1 fewer mul/elem)
//  - bf16 pair-pack via v_perm (3 ops/2 vals), singles via +0x8000>>16
//  - rcpf for dir + gelu divides
struct __align__(16) SMem {
    unsigned short wbuf[64*72];     // 9216 B staged weight slice
    union {
        float  dist[128*17];        // live until dir phase
        unsigned short hidT[128*72];// live in MLP1/MLP2 (after barrier)
    };
    unsigned short pairT[128*72];   // bf16 [s][k<=64], stride 72
    float  loc[LD];
    float  posall3[ATOT*3];
    float  pl[33];
    float  rot[9];
    float  ca3[3];
    float  wtypef[7*PD];
    float  basev[PD];
    float  gatevv[PD];
    float  lnsc[PD], lnof[PD];
    float  b1v[HD], b2v[PD];
    int    typef[SS];
    float  maskf[SS];
    float  red[4*PD];
    float  fin[PD];
    float  cnt;
};

// dir element: own-row coords in registers; rcpf (~1ULP; r12's failure was
// cvtpk operand semantics — rcpf error is ~1e-7, cannot produce e-2 errors)
__device__ __forceinline__ float dirv2(const SMem& sm, float px, float py, float pz,
                                       int sl, int k){
    int kc = (k < 48) ? k : 47;
    int a = (kc * 21846) >> 16;     // kc/3
    int c = kc - 3*a;
    float pc = (c == 0) ? px : ((c == 1) ? py : pz);
    float e = (pc - sm.posall3[a*3+c]) * __builtin_amdgcn_rcpf(sm.dist[sl*17 + a]);
    return (k < 48) ? e : 0.0f;
}

// stage a [64 rows][64 k] slice from global into wbuf (row stride 72).
__device__ __forceinline__ void stageW(const unsigned short* __restrict__ src, int stride,
                                       unsigned short* dst, int tid){
    __syncthreads();
    int r = tid >> 3, s = (tid & 7) * 8;
    *(u32x4*)&dst[r*72 + s]      = *(const u32x4*)&src[r*stride + s];
    *(u32x4*)&dst[(r+32)*72 + s] = *(const u32x4*)&src[(r+32)*stride + s];
    __syncthreads();
}

// RBF A-fragment: val_j = exp2(-(d*A - cA_j)^2), A = sqrt(log2e)/0.75
// cA step = 0.8*A = 1.28119724
#define RBF_FRAG(av, sl) do {                                               \
    float dA_ = sm.dist[(sl)*17 + 2*kk + (g>>1)] * 1.60149654f;             \
    float z0_ = dA_ - (b0c + 0.00000000f);                                  \
    float z1_ = dA_ - (b0c + 1.28119724f);                                  \
    float z2_ = dA_ - (b0c + 2.56239447f);                                  \
    float z3_ = dA_ - (b0c + 3.84359171f);                                  \
    float z4_ = dA_ - (b0c + 5.12478894f);                                  \
    float z5_ = dA_ - (b0c + 6.40598618f);                                  \
    float z6_ = dA_ - (b0c + 7.68718342f);                                  \
    float z7_ = dA_ - (b0c + 8.96838065f);                                  \
    unsigned int w0_ = pk2bf(__builtin_amdgcn_exp2f((-z0_)*z0_),            \
                             __builtin_amdgcn_exp2f((-z1_)*z1_));           \
    unsigned int w1_ = pk2bf(__builtin_amdgcn_exp2f((-z2_)*z2_),            \
                             __builtin_amdgcn_exp2f((-z3_)*z3_));           \
    unsigned int w2_ = pk2bf(__builtin_amdgcn_exp2f((-z4_)*z4_),            \
                             __builtin_amdgcn_exp2f((-z5_)*z5_));           \
    unsigned int w3_ = pk2bf(__builtin_amdgcn_exp2f((-z6_)*z6_),            \
                             __builtin_amdgcn_exp2f((-z7_)*z7_));           \
    av = __builtin_bit_cast(bf16x8, (u32x4){w0_, w1_, w2_, w3_});           \
} while(0)

__global__ __launch_bounds__(256, 3)
void smol_fused(const float* __restrict__ g_local,
                const float* __restrict__ g_pos,
                const int*   __restrict__ g_type,
                const float* __restrict__ g_spos,
                const int*   __restrict__ g_mask,
                const float* __restrict__ w_points,
                const float* __restrict__ w_local,
                const float* __restrict__ w_type,
                const float* __restrict__ ln_scale,
                const float* __restrict__ ln_offset,
                const float* __restrict__ b_mlp1,
                const float* __restrict__ b_mlp2,
                const float* __restrict__ w_gate,
                const float* __restrict__ w_out,
                const unsigned short* __restrict__ ws,
                float* __restrict__ g_out)
{
    __shared__ SMem sm;
    const int n    = blockIdx.x;
    const int tid  = threadIdx.x;
    const int wv   = tid >> 6;        // wave 0..3 : owns rows 32wv..32wv+31
    const int lane = tid & 63;
    const int cB   = lane & 15;       // A-row / B-col selector
    const int g    = lane >> 4;       // k-subgroup 0..3
    const int sl0  = 32*wv + cB;      // tile-0 A row
    const int sl1  = sl0 + 16;        // tile-1 A row

    const unsigned short* wsD   = ws;
    const unsigned short* wsDir = ws + 16384;
    const unsigned short* wsM1  = ws + 20480;
    const unsigned short* wsM2  = ws + 28672;

    // ---------- stage per-n data + small weights ----------
    sm.loc[tid] = g_local[n*LD + tid];
    sm.wtypef[tid] = w_type[tid];
    if (tid < 7*PD - 256) sm.wtypef[256 + tid] = w_type[256 + tid];
    if (tid < PD){ sm.lnsc[tid] = ln_scale[tid]; sm.lnof[tid] = ln_offset[tid]; sm.b2v[tid] = b_mlp2[tid]; }
    if (tid < HD) sm.b1v[tid] = b_mlp1[tid];
    if (tid < SS){ sm.typef[tid] = g_type[n*SS + tid];
                   sm.maskf[tid] = (g_mask[n*SS + tid] != 0) ? 1.0f : 0.0f; }
    if (tid >= 128 && tid < 128 + A0C*3) sm.posall3[tid-128] = g_pos[n*A0C*3 + (tid-128)];
    __syncthreads();

    // ---------- per-n precompute ----------
    if (tid < 33){
        float a = 0.f;
        for (int i = 0; i < LD; ++i) a += sm.loc[i] * w_points[i*33 + tid];
        sm.pl[tid] = a;
    } else if (tid >= 64 && tid < 128){
        int p = tid - 64; float a = 0.f;
        for (int i = 0; i < LD; ++i) a += sm.loc[i] * w_local[i*PD + p];
        sm.basev[p] = a;
    } else if (tid >= 128 && tid < 192){
        int p = tid - 128; float a = 0.f;
        for (int i = 0; i < LD; ++i) a += sm.loc[i] * w_gate[i*PD + p];
        sm.gatevv[p] = gelu_f(a);
    } else if (tid == 255){
        float nx=sm.posall3[0], ny=sm.posall3[1], nz=sm.posall3[2];
        float cax=sm.posall3[3], cay=sm.posall3[4], caz=sm.posall3[5];
        float cx=sm.posall3[6], cy=sm.posall3[7], cz=sm.posall3[8];
        float v1x=cx-cax, v1y=cy-cay, v1z=cz-caz;
        float r = 1.0f/sqrtf(v1x*v1x + v1y*v1y + v1z*v1z + 1e-6f);
        float e1x=v1x*r, e1y=v1y*r, e1z=v1z*r;
        float v2x=nx-cax, v2y=ny-cay, v2z=nz-caz;
        float dp = e1x*v2x + e1y*v2y + e1z*v2z;
        float u2x=v2x-e1x*dp, u2y=v2y-e1y*dp, u2z=v2z-e1z*dp;
        r = 1.0f/sqrtf(u2x*u2x + u2y*u2y + u2z*u2z + 1e-6f);
        float e2x=u2x*r, e2y=u2y*r, e2z=u2z*r;
        float e3x=e1y*e2z-e1z*e2y, e3y=e1z*e2x-e1x*e2z, e3z=e1x*e2y-e1y*e2x;
        sm.rot[0]=e1x; sm.rot[1]=e2x; sm.rot[2]=e3x;
        sm.rot[3]=e1y; sm.rot[4]=e2y; sm.rot[5]=e3y;
        sm.rot[6]=e1z; sm.rot[7]=e2z; sm.rot[8]=e3z;
        sm.ca3[0]=cax; sm.ca3[1]=cay; sm.ca3[2]=caz;
    } else if (tid == 254){
        float c = 0.f;
        for (int s = 0; s < SS; ++s) c += sm.maskf[s];
        sm.cnt = c;
    }
    __syncthreads();
    if (tid < 33){
        int k = tid / 3, i2 = tid - k*3;
        sm.posall3[(A0C + k)*3 + i2] =
            sm.rot[i2*3+0]*sm.pl[k*3+0] + sm.rot[i2*3+1]*sm.pl[k*3+1] +
            sm.rot[i2*3+2]*sm.pl[k*3+2] + sm.ca3[i2];
    }
    __syncthreads();   // posall3 visible to all waves

    // own-row smol coords in REGISTERS (no LDS handoff)
    const float px0 = g_spos[(n*SS + sl0)*3 + 0];
    const float py0 = g_spos[(n*SS + sl0)*3 + 1];
    const float pz0 = g_spos[(n*SS + sl0)*3 + 2];
    const float px1 = g_spos[(n*SS + sl1)*3 + 0];
    const float py1 = g_spos[(n*SS + sl1)*3 + 1];
    const float pz1 = g_spos[(n*SS + sl1)*3 + 2];

    // dist for this wave's 32 rows (cross-lane reads only after next barrier)
    #pragma unroll
    for (int aa = 0; aa < 4; ++aa){
        int a = g*4 + aa;
        float ax = sm.posall3[a*3+0], ay = sm.posall3[a*3+1], az = sm.posall3[a*3+2];
        float rx0 = px0-ax, ry0 = py0-ay, rz0 = pz0-az;
        sm.dist[sl0*17 + a] = sqrtf(rx0*rx0 + ry0*ry0 + rz0*rz0 + 1e-6f);
        float rx1 = px1-ax, ry1 = py1-ay, rz1 = pz1-az;
        sm.dist[sl1*17 + a] = sqrtf(rx1*rx1 + ry1*ry1 + rz1*rz1 + 1e-6f);
    }

    const float b0c = (float)((g&1) * 8) * 1.28119724f;

    // ---- pair GEMM: dist-RBF (K=256), B staged once in 4 k-slices ----
    f32x4 accP0 = {0.f,0.f,0.f,0.f}, accP1 = accP0, accP2 = accP0, accP3 = accP0;  // tile 0
    f32x4 accQ0 = accP0, accQ1 = accP0, accQ2 = accP0, accQ3 = accP0;              // tile 1

    for (int h = 0; h < 4; ++h){
        stageW(wsD + h*64, 256, sm.wbuf, tid);
        #pragma unroll
        for (int kkl = 0; kkl < 2; ++kkl){
            const int kk = h*2 + kkl;
            bf16x8 av0, av1;
            RBF_FRAG(av0, sl0);
            RBF_FRAG(av1, sl1);
            const unsigned short* bb = &sm.wbuf[cB*72 + kkl*32 + g*8];
            bf16x8 B0 = *(const bf16x8*)(bb +  0*72);
            bf16x8 B1 = *(const bf16x8*)(bb + 16*72);
            bf16x8 B2 = *(const bf16x8*)(bb + 32*72);
            bf16x8 B3 = *(const bf16x8*)(bb + 48*72);
            accP0 = MFMA(av0, B0, accP0);  accQ0 = MFMA(av1, B0, accQ0);
            accP1 = MFMA(av0, B1, accP1);  accQ1 = MFMA(av1, B1, accQ1);
            accP2 = MFMA(av0, B2, accP2);  accQ2 = MFMA(av1, B2, accQ2);
            accP3 = MFMA(av0, B3, accP3);  accQ3 = MFMA(av1, B3, accQ3);
        }
    }

    // ---- + directions @ w_dir (K=48 pad 64), one staged slice ----
    stageW(wsDir, 64, sm.wbuf, tid);
    #pragma unroll
    for (int kk = 0; kk < 2; ++kk){
        int k0 = kk*32 + g*8;
        unsigned int a0w0 = pk2bf(dirv2(sm,px0,py0,pz0,sl0,k0+0), dirv2(sm,px0,py0,pz0,sl0,k0+1));
        unsigned int a0w1 = pk2bf(dirv2(sm,px0,py0,pz0,sl0,k0+2), dirv2(sm,px0,py0,pz0,sl0,k0+3));
        unsigned int a0w2 = pk2bf(dirv2(sm,px0,py0,pz0,sl0,k0+4), dirv2(sm,px0,py0,pz0,sl0,k0+5));
        unsigned int a0w3 = pk2bf(dirv2(sm,px0,py0,pz0,sl0,k0+6), dirv2(sm,px0,py0,pz0,sl0,k0+7));
        bf16x8 av0 = __builtin_bit_cast(bf16x8, (u32x4){a0w0,a0w1,a0w2,a0w3});
        unsigned int a1w0 = pk2bf(dirv2(sm,px1,py1,pz1,sl1,k0+0), dirv2(sm,px1,py1,pz1,sl1,k0+1));
        unsigned int a1w1 = pk2bf(dirv2(sm,px1,py1,pz1,sl1,k0+2), dirv2(sm,px1,py1,pz1,sl1,k0+3));
        unsigned int a1w2 = pk2bf(dirv2(sm,px1,py1,pz1,sl1,k0+4), dirv2(sm,px1,py1,pz1,sl1,k0+5));
        unsigned int a1w3 = pk2bf(dirv2(sm,px1,py1,pz1,sl1,k0+6), dirv2(sm,px1,py1,pz1,sl1,k0+7));
        bf16x8 av1 = __builtin_bit_cast(bf16x8, (u32x4){a1w0,a1w1,a1w2,a1w3});
        const unsigned short* bb = &sm.wbuf[cB*72 + k0];
        bf16x8 B0 = *(const bf16x8*)(bb +  0*72);
        bf16x8 B1 = *(const bf16x8*)(bb + 16*72);
        bf16x8 B2 = *(const bf16x8*)(bb + 32*72);
        bf16x8 B3 = *(const bf16x8*)(bb + 48*72);
        accP0 = MFMA(av0, B0, accP0);  accQ0 = MFMA(av1, B0, accQ0);
        accP1 = MFMA(av0, B1, accP1);  accQ1 = MFMA(av1, B1, accQ1);
        accP2 = MFMA(av0, B2, accP2);  accQ2 = MFMA(av1, B2, accQ2);
        accP3 = MFMA(av0, B3, accP3);  accQ3 = MFMA(av1, B3, accQ3);
    }

    // ---- epilogue: + base + wtype, LayerNorm, bf16 stores to pairT ----
    #pragma unroll
    for (int t = 0; t < 2; ++t){
        #pragma unroll
        for (int r = 0; r < 4; ++r){
            int slr = 32*wv + 16*t + g*4 + r;
            int ty  = sm.typef[slr];
            float a0 = (t==0 ? accP0[r] : accQ0[r]);
            float a1 = (t==0 ? accP1[r] : accQ1[r]);
            float a2 = (t==0 ? accP2[r] : accQ2[r]);
            float a3 = (t==0 ? accP3[r] : accQ3[r]);
            float v0 = a0 + sm.basev[cB +  0] + sm.wtypef[ty*PD + cB +  0];
            float v1 = a1 + sm.basev[cB + 16] + sm.wtypef[ty*PD + cB + 16];
            float v2 = a2 + sm.basev[cB + 32] + sm.wtypef[ty*PD + cB + 32];
            float v3 = a3 + sm.basev[cB + 48] + sm.wtypef[ty*PD + cB + 48];
            float ssum = v0+v1+v2+v3;
            ssum += __shfl_xor(ssum,1); ssum += __shfl_xor(ssum,2);
            ssum += __shfl_xor(ssum,4); ssum += __shfl_xor(ssum,8);
            float mu = ssum * (1.0f/64.0f);
            float d0=v0-mu, d1=v1-mu, d2=v2-mu, d3=v3-mu;
            float sq = d0*d0+d1*d1+d2*d2+d3*d3;
            sq += __shfl_xor(sq,1); sq += __shfl_xor(sq,2);
            sq += __shfl_xor(sq,4); sq += __shfl_xor(sq,8);
            float inv = 1.0f / sqrtf(sq*(1.0f/64.0f) + 1e-5f);
            unsigned short* pr = &sm.pairT[slr*72];
            pr[cB +  0] = f2bfhu(d0*inv*sm.lnsc[cB +  0] + sm.lnof[cB +  0]);
            pr[cB + 16] = f2bfhu(d1*inv*sm.lnsc[cB + 16] + sm.lnof[cB + 16]);
            pr[cB + 32] = f2bfhu(d2*inv*sm.lnsc[cB + 32] + sm.lnof[cB + 32]);
            pr[cB + 48] = f2bfhu(d3*inv*sm.lnsc[cB + 48] + sm.lnof[cB + 48]);
        }
    }

    // ==== MLP1/MLP2 interleaved in k-halves (r15 schedule) ====
    f32x4 accO0 = {0.f,0.f,0.f,0.f}, accO1 = accO0, accO2 = accO0, accO3 = accO0;  // tile 0
    f32x4 accN0 = accO0, accN1 = accO0, accN2 = accO0, accN3 = accO0;              // tile 1

    // ---- MLP1 half a (hidden cols 0..63) ----
    f32x4 accH0 = {0.f,0.f,0.f,0.f}, accH1 = accH0, accH2 = accH0, accH3 = accH0;
    f32x4 accI0 = accH0, accI1 = accH0, accI2 = accH0, accI3 = accH0;
    stageW(wsM1, 64, sm.wbuf, tid);     // leading barrier publishes pairT + retires dist
    #pragma unroll
    for (int kk = 0; kk < 2; ++kk){
        bf16x8 a0 = *(const bf16x8*)&sm.pairT[sl0*72 + kk*32 + g*8];
        bf16x8 a1 = *(const bf16x8*)&sm.pairT[sl1*72 + kk*32 + g*8];
        const unsigned short* bb = &sm.wbuf[cB*72 + kk*32 + g*8];
        bf16x8 B0 = *(const bf16x8*)(bb + 0*16*72);
        bf16x8 B1 = *(const bf16x8*)(bb + 1*16*72);
        bf16x8 B2 = *(const bf16x8*)(bb + 2*16*72);
        bf16x8 B3 = *(const bf16x8*)(bb + 3*16*72);
        accH0 = MFMA(a0, B0, accH0);  accI0 = MFMA(a1, B0, accI0);
        accH1 = MFMA(a0, B1, accH1);  accI1 = MFMA(a1, B1, accI1);
        accH2 = MFMA(a0, B2, accH2);  accI2 = MFMA(a1, B2, accI2);
        accH3 = MFMA(a0, B3, accH3);  accI3 = MFMA(a1, B3, accI3);
    }
    #pragma unroll
    for (int r = 0; r < 4; ++r){
        int slr0 = 32*wv + g*4 + r;
        unsigned short* hr0 = &sm.hidT[slr0*72];
        hr0[cB + 0*16] = f2bfhu(gelu_f(accH0[r] + sm.b1v[cB + 0*16]));
        hr0[cB + 1*16] = f2bfhu(gelu_f(accH1[r] + sm.b1v[cB + 1*16]));
        hr0[cB + 2*16] = f2bfhu(gelu_f(accH2[r] + sm.b1v[cB + 2*16]));
        hr0[cB + 3*16] = f2bfhu(gelu_f(accH3[r] + sm.b1v[cB + 3*16]));
        unsigned short* hr1 = &sm.hidT[(slr0+16)*72];
        hr1[cB + 0*16] = f2bfhu(gelu_f(accI0[r] + sm.b1v[cB + 0*16]));
        hr1[cB + 1*16] = f2bfhu(gelu_f(accI1[r] + sm.b1v[cB + 1*16]));
        hr1[cB + 2*16] = f2bfhu(gelu_f(accI2[r] + sm.b1v[cB + 2*16]));
        hr1[cB + 3*16] = f2bfhu(gelu_f(accI3[r] + sm.b1v[cB + 3*16]));
    }

    // ---- MLP2 k-half 0 (k = 0..63) ----
    stageW(wsM2, 128, sm.wbuf, tid);    // leading barrier publishes hidT half a
    #pragma unroll
    for (int kkl = 0; kkl < 2; ++kkl){
        bf16x8 a0 = *(const bf16x8*)&sm.hidT[sl0*72 + kkl*32 + g*8];
        bf16x8 a1 = *(const bf16x8*)&sm.hidT[sl1*72 + kkl*32 + g*8];
        const unsigned short* bb = &sm.wbuf[cB*72 + kkl*32 + g*8];
        bf16x8 B0 = *(const bf16x8*)(bb + 0*16*72);
        bf16x8 B1 = *(const bf16x8*)(bb + 1*16*72);
        bf16x8 B2 = *(const bf16x8*)(bb + 2*16*72);
        bf16x8 B3 = *(const bf16x8*)(bb + 3*16*72);
        accO0 = MFMA(a0, B0, accO0);  accN0 = MFMA(a1, B0, accN0);
        accO1 = MFMA(a0, B1, accO1);  accN1 = MFMA(a1, B1, accN1);
        accO2 = MFMA(a0, B2, accO2);  accN2 = MFMA(a1, B2, accN2);
        accO3 = MFMA(a0, B3, accO3);  accN3 = MFMA(a1, B3, accN3);
    }

    // ---- MLP1 half b (hidden cols 64..127) ----
    f32x4 accH4 = {0.f,0.f,0.f,0.f}, accH5 = accH4, accH6 = accH4, accH7 = accH4;
    f32x4 accI4 = accH4, accI5 = accH4, accI6 = accH4, accI7 = accH4;
    stageW(wsM1 + 64*64, 64, sm.wbuf, tid);   // leading barrier retires hidT-half-a reads
    #pragma unroll
    for (int kk = 0; kk < 2; ++kk){
        bf16x8 a0 = *(const bf16x8*)&sm.pairT[sl0*72 + kk*32 + g*8];
        bf16x8 a1 = *(const bf16x8*)&sm.pairT[sl1*72 + kk*32 + g*8];
        const unsigned short* bb = &sm.wbuf[cB*72 + kk*32 + g*8];
        bf16x8 B0 = *(const bf16x8*)(bb + 0*16*72);
        bf16x8 B1 = *(const bf16x8*)(bb + 1*16*72);
        bf16x8 B2 = *(const bf16x8*)(bb + 2*16*72);
        bf16x8 B3 = *(const bf16x8*)(bb + 3*16*72);
        accH4 = MFMA(a0, B0, accH4);  accI4 = MFMA(a1, B0, accI4);
        accH5 = MFMA(a0, B1, accH5);  accI5 = MFMA(a1, B1, accI5);
        accH6 = MFMA(a0, B2, accH6);  accI6 = MFMA(a1, B2, accI6);
        accH7 = MFMA(a0, B3, accH7);  accI7 = MFMA(a1, B3, accI7);
    }
    #pragma unroll
    for (int r = 0; r < 4; ++r){
        int slr0 = 32*wv + g*4 + r;
        unsigned short* hr0 = &sm.hidT[slr0*72];
        hr0[cB + 0*16] = f2bfhu(gelu_f(accH4[r] + sm.b1v[cB + 4*16]));
        hr0[cB + 1*16] = f2bfhu(gelu_f(accH5[r] + sm.b1v[cB + 5*16]));
        hr0[cB + 2*16] = f2bfhu(gelu_f(accH6[r] + sm.b1v[cB + 6*16]));
        hr0[cB + 3*16] = f2bfhu(gelu_f(accH7[r] + sm.b1v[cB + 7*16]));
        unsigned short* hr1 = &sm.hidT[(slr0+16)*72];
        hr1[cB + 0*16] = f2bfhu(gelu_f(accI4[r] + sm.b1v[cB + 4*16]));
        hr1[cB + 1*16] = f2bfhu(gelu_f(accI5[r] + sm.b1v[cB + 5*16]));
        hr1[cB + 2*16] = f2bfhu(gelu_f(accI6[r] + sm.b1v[cB + 6*16]));
        hr1[cB + 3*16] = f2bfhu(gelu_f(accI7[r] + sm.b1v[cB + 7*16]));
    }

    // ---- MLP2 k-half 1 (k = 64..127) ----
    stageW(wsM2 + 64, 128, sm.wbuf, tid);     // leading barrier publishes hidT half b
    #pragma unroll
    for (int kkl = 0; kkl < 2; ++kkl){
        bf16x8 a0 = *(const bf16x8*)&sm.hidT[sl0*72 + kkl*32 + g*8];
        bf16x8 a1 = *(const bf16x8*)&sm.hidT[sl1*72 + kkl*32 + g*8];
        const unsigned short* bb = &sm.wbuf[cB*72 + kkl*32 + g*8];
        bf16x8 B0 = *(const bf16x8*)(bb + 0*16*72);
        bf16x8 B1 = *(const bf16x8*)(bb + 1*16*72);
        bf16x8 B2 = *(const bf16x8*)(bb + 2*16*72);
        bf16x8 B3 = *(const bf16x8*)(bb + 3*16*72);
        accO0 = MFMA(a0, B0, accO0);  accN0 = MFMA(a1, B0, accN0);
        accO1 = MFMA(a0, B1, accO1);  accN1 = MFMA(a1, B1, accN1);
        accO2 = MFMA(a0, B2, accO2);  accN2 = MFMA(a1, B2, accN2);
        accO3 = MFMA(a0, B3, accO3);  accN3 = MFMA(a1, B3, accN3);
    }

    float pooled0 = 0.f, pooled1 = 0.f, pooled2 = 0.f, pooled3 = 0.f;
    #pragma unroll
    for (int r = 0; r < 4; ++r){
        float m0f = sm.maskf[32*wv + g*4 + r];
        float m1f = sm.maskf[32*wv + 16 + g*4 + r];
        pooled0 += m0f * accO0[r] + m1f * accN0[r];
        pooled1 += m0f * accO1[r] + m1f * accN1[r];
        pooled2 += m0f * accO2[r] + m1f * accN2[r];
        pooled3 += m0f * accO3[r] + m1f * accN3[r];
    }

    // ---- reduce pooled: across g-groups (same col), then across waves ----
    pooled0 += __shfl_xor(pooled0,16); pooled0 += __shfl_xor(pooled0,32);
    pooled1 += __shfl_xor(pooled1,16); pooled1 += __shfl_xor(pooled1,32);
    pooled2 += __shfl_xor(pooled2,16); pooled2 += __shfl_xor(pooled2,32);
    pooled3 += __shfl_xor(pooled3,16); pooled3 += __shfl_xor(pooled3,32);
    if (g == 0){
        sm.red[wv*PD + cB +  0] = pooled0;
        sm.red[wv*PD + cB + 16] = pooled1;
        sm.red[wv*PD + cB + 32] = pooled2;
        sm.red[wv*PD + cB + 48] = pooled3;
    }
    __syncthreads();
    if (tid < PD){
        float v = sm.red[tid] + sm.red[PD + tid] + sm.red[2*PD + tid] + sm.red[3*PD + tid];
        float mc = fmaxf(sm.cnt, 1.0f);
        v = (v + sm.cnt * sm.b2v[tid]) / mc;        // adds b2 exactly like ref (0 if cnt==0)
        sm.fin[tid] = sm.gatevv[tid] * v;
    }
    __syncthreads();
    {
        float a = 0.f;
        #pragma unroll 4
        for (int p = 0; p < PD; ++p) a += sm.fin[p] * w_out[p*LD + tid];
        g_out[n*LD + tid] = a;
    }
}

extern "C" void kernel_launch(void* const* d_in, const int* in_sizes, int n_in,
                              void* d_out, int out_size, void* d_ws, size_t ws_size,
                              hipStream_t stream)
{
    (void)in_sizes; (void)n_in; (void)out_size; (void)ws_size;
    const float* g_local   = (const float*)d_in[0];
    const float* g_pos     = (const float*)d_in[1];
    const int*   g_type    = (const int*)  d_in[2];
    const float* g_spos    = (const float*)d_in[3];
    const int*   g_mask    = (const int*)  d_in[4];
    const float* w_points  = (const float*)d_in[5];
    const float* w_type    = (const float*)d_in[6];
    const float* w_local   = (const float*)d_in[7];
    const float* w_dir     = (const float*)d_in[8];
    const float* w_dist    = (const float*)d_in[9];
    const float* ln_scale  = (const float*)d_in[10];
    const float* ln_offset = (const float*)d_in[11];
    const float* w_mlp1    = (const float*)d_in[12];
    const float* b_mlp1    = (const float*)d_in[13];
    const float* w_mlp2    = (const float*)d_in[14];
    const float* b_mlp2    = (const float*)d_in[15];
    const float* w_gate    = (const float*)d_in[16];
    const float* w_out     = (const float*)d_in[17];

    unsigned short* ws = (unsigned short*)d_ws;   // 73728 B

    smol_prep<<<dim3(144), dim3(256), 0, stream>>>(w_dist, w_dir, w_mlp1, w_mlp2, ws);

    smol_fused<<<dim3(NRES), dim3(256), 0, stream>>>(
        g_local, g_pos, g_type, g_spos, g_mask,
        w_points, w_local, w_type, ln_scale, ln_offset,
        b_mlp1, b_mlp2, w_gate, w_out, ws, (float*)d_out);
}

// Round 17
// 138.593 us; speedup vs baseline: 2.0497x; 1.0265x over previous
//
#include <hip/hip_runtime.h>
#include <math.h>

#define NRES 4096
#define SS   128
#define A0C  5
#define ATOT 16
#define LD   256
#define PD   64
#define HD   128

typedef __attribute__((ext_vector_type(8))) short bf16x8;
typedef __attribute__((ext_vector_type(4))) float f32x4;
typedef __attribute__((ext_vector_type(4))) unsigned int u32x4;

__device__ __forceinline__ unsigned short f2bf(float x){
    unsigned int u = __builtin_bit_cast(unsigned int, x);
    unsigned int r = u + 0x7FFFu + ((u >> 16) & 1u);   // RNE to bf16 (prep only)
    return (unsigned short)(r >> 16);
}
// cheap conversions (r16): round-half-up, ties differ from RNE only at exact ties.
__device__ __forceinline__ unsigned short f2bfhu(float x){
    return (unsigned short)((__builtin_bit_cast(unsigned int, x) + 0x8000u) >> 16);
}
// pack two f32 -> one u32 of 2 bf16 (lo,hi) in 3 VALU ops via v_perm_b32.
__device__ __forceinline__ unsigned int pk2bf(float lo, float hi){
    unsigned int a = __builtin_bit_cast(unsigned int, lo) + 0x8000u;
    unsigned int b = __builtin_bit_cast(unsigned int, hi) + 0x8000u;
    return __builtin_amdgcn_perm(b, a, 0x07060302u);
}
__device__ __forceinline__ float gelu_f(float x){
    float e = __expf(-1.59576912f * x * (1.0f + 0.044715f * x * x));
    return x * __builtin_amdgcn_rcpf(1.0f + e);
}
__device__ __forceinline__ f32x4 MFMA(bf16x8 a, bf16x8 b, f32x4 c){
    return __builtin_amdgcn_mfma_f32_16x16x32_bf16(a, b, c, 0, 0, 0);
}

// ---------------- prep: transpose+convert weights to bf16 in d_ws ----------------
// layout (ushort elements)  [identical to r5..r16 — 73728 B total]:
//   [0)      wsD   [64 n][256 k]   (w_dist^T)
//   [16384)  wsDir [64 n][64 k]    (w_dir^T, k>=48 zero)
//   [20480)  wsM1  [128 n][64 k]   (w_mlp1^T)
//   [28672)  wsM2  [64 n][128 k]   (w_mlp2^T)
__global__ void smol_prep(const float* __restrict__ wdist, const float* __restrict__ wdir,
                          const float* __restrict__ wm1,  const float* __restrict__ wm2,
                          unsigned short* __restrict__ ws)
{
    int i = blockIdx.x * 256 + threadIdx.x;
    if (i < 16384){
        int nn = i >> 8, k = i & 255;
        ws[i] = f2bf(wdist[k*64 + nn]);
    } else if (i < 20480){
        int j = i - 16384; int nn = j >> 6, k = j & 63;
        ws[i] = (k < 48) ? f2bf(wdir[k*64 + nn]) : (unsigned short)0;
    } else if (i < 28672){
        int j = i - 20480; int nn = j >> 6, k = j & 63;
        ws[i] = f2bf(wm1[k*128 + nn]);
    } else if (i < 36864){
        int j = i - 28672; int nn = j >> 7, k = j & 127;
        ws[i] = f2bf(wm2[k*64 + nn]);
    }
}

// ---------------- main fused kernel ----------------
// r17 = r16 EXACTLY (math, layouts, barrier semantics) + T14 async-STAGE split:
// each weight slice's global loads issue into registers ONE STAGE AHEAD
// (overlapping the previous phase's MFMA/VALU); the barrier bracket contains
// only the two ds_write_b128. r14 showed the 8-wave reshape was harmful;
// this applies the pipeline to the proven 4-wave structure in isolation.
struct __align__(16) SMem {
    unsigned short wbuf[64*72];     // 9216 B staged weight slice
    union {
        float  dist[128*17];        // live until dir phase
        unsigned short hidT[128*72];// live in MLP1/MLP2 (after barrier)
    };
    unsigned short pairT[128*72];   // bf16 [s][k<=64], stride 72
    float  loc[LD];
    float  posall3[ATOT*3];
    float  pl[33];
    float  rot[9];
    float  ca3[3];
    float  wtypef[7*PD];
    float  basev[PD];
    float  gatevv[PD];
    float  lnsc[PD], lnof[PD];
    float  b1v[HD], b2v[PD];
    int    typef[SS];
    float  maskf[SS];
    float  red[4*PD];
    float  fin[PD];
    float  cnt;
};

__device__ __forceinline__ float dirv2(const SMem& sm, float px, float py, float pz,
                                       int sl, int k){
    int kc = (k < 48) ? k : 47;
    int a = (kc * 21846) >> 16;     // kc/3
    int c = kc - 3*a;
    float pc = (c == 0) ? px : ((c == 1) ? py : pz);
    float e = (pc - sm.posall3[a*3+c]) * __builtin_amdgcn_rcpf(sm.dist[sl*17 + a]);
    return (k < 48) ? e : 0.0f;
}

// r17: issue a slice's global loads into registers (no barrier, no LDS).
__device__ __forceinline__ void loadStage(const unsigned short* __restrict__ src, int stride,
                                          int tid, u32x4& a, u32x4& b){
    int r = tid >> 3, s = (tid & 7) * 8;
    a = *(const u32x4*)&src[r*stride + s];
    b = *(const u32x4*)&src[(r+32)*stride + s];
}
// publish a prefetched slice: barrier (retire prior wbuf reads + publish all
// prior LDS writes) -> 2x ds_write_b128 -> barrier (publish slice).
__device__ __forceinline__ void pubStage(u32x4 a, u32x4 b, unsigned short* dst, int tid){
    __syncthreads();
    int r = tid >> 3, s = (tid & 7) * 8;
    *(u32x4*)&dst[r*72 + s]      = a;
    *(u32x4*)&dst[(r+32)*72 + s] = b;
    __syncthreads();
}

// RBF A-fragment: val_j = exp2(-(d*A - cA_j)^2), A = sqrt(log2e)/0.75
#define RBF_FRAG(av, sl) do {                                               \
    float dA_ = sm.dist[(sl)*17 + 2*kk + (g>>1)] * 1.60149654f;             \
    float z0_ = dA_ - (b0c + 0.00000000f);                                  \
    float z1_ = dA_ - (b0c + 1.28119724f);                                  \
    float z2_ = dA_ - (b0c + 2.56239447f);                                  \
    float z3_ = dA_ - (b0c + 3.84359171f);                                  \
    float z4_ = dA_ - (b0c + 5.12478894f);                                  \
    float z5_ = dA_ - (b0c + 6.40598618f);                                  \
    float z6_ = dA_ - (b0c + 7.68718342f);                                  \
    float z7_ = dA_ - (b0c + 8.96838065f);                                  \
    unsigned int w0_ = pk2bf(__builtin_amdgcn_exp2f((-z0_)*z0_),            \
                             __builtin_amdgcn_exp2f((-z1_)*z1_));           \
    unsigned int w1_ = pk2bf(__builtin_amdgcn_exp2f((-z2_)*z2_),            \
                             __builtin_amdgcn_exp2f((-z3_)*z3_));           \
    unsigned int w2_ = pk2bf(__builtin_amdgcn_exp2f((-z4_)*z4_),            \
                             __builtin_amdgcn_exp2f((-z5_)*z5_));           \
    unsigned int w3_ = pk2bf(__builtin_amdgcn_exp2f((-z6_)*z6_),            \
                             __builtin_amdgcn_exp2f((-z7_)*z7_));           \
    av = __builtin_bit_cast(bf16x8, (u32x4){w0_, w1_, w2_, w3_});           \
} while(0)

__global__ __launch_bounds__(256, 3)
void smol_fused(const float* __restrict__ g_local,
                const float* __restrict__ g_pos,
                const int*   __restrict__ g_type,
                const float* __restrict__ g_spos,
                const int*   __restrict__ g_mask,
                const float* __restrict__ w_points,
                const float* __restrict__ w_local,
                const float* __restrict__ w_type,
                const float* __restrict__ ln_scale,
                const float* __restrict__ ln_offset,
                const float* __restrict__ b_mlp1,
                const float* __restrict__ b_mlp2,
                const float* __restrict__ w_gate,
                const float* __restrict__ w_out,
                const unsigned short* __restrict__ ws,
                float* __restrict__ g_out)
{
    __shared__ SMem sm;
    const int n    = blockIdx.x;
    const int tid  = threadIdx.x;
    const int wv   = tid >> 6;        // wave 0..3 : owns rows 32wv..32wv+31
    const int lane = tid & 63;
    const int cB   = lane & 15;       // A-row / B-col selector
    const int g    = lane >> 4;       // k-subgroup 0..3
    const int sl0  = 32*wv + cB;      // tile-0 A row
    const int sl1  = sl0 + 16;        // tile-1 A row

    const unsigned short* wsD   = ws;
    const unsigned short* wsDir = ws + 16384;
    const unsigned short* wsM1  = ws + 20480;
    const unsigned short* wsM2  = ws + 28672;

    // ---------- stage per-n data + small weights ----------
    sm.loc[tid] = g_local[n*LD + tid];
    sm.wtypef[tid] = w_type[tid];
    if (tid < 7*PD - 256) sm.wtypef[256 + tid] = w_type[256 + tid];
    if (tid < PD){ sm.lnsc[tid] = ln_scale[tid]; sm.lnof[tid] = ln_offset[tid]; sm.b2v[tid] = b_mlp2[tid]; }
    if (tid < HD) sm.b1v[tid] = b_mlp1[tid];
    if (tid < SS){ sm.typef[tid] = g_type[n*SS + tid];
                   sm.maskf[tid] = (g_mask[n*SS + tid] != 0) ? 1.0f : 0.0f; }
    if (tid >= 128 && tid < 128 + A0C*3) sm.posall3[tid-128] = g_pos[n*A0C*3 + (tid-128)];
    __syncthreads();

    // ---------- per-n precompute ----------
    if (tid < 33){
        float a = 0.f;
        for (int i = 0; i < LD; ++i) a += sm.loc[i] * w_points[i*33 + tid];
        sm.pl[tid] = a;
    } else if (tid >= 64 && tid < 128){
        int p = tid - 64; float a = 0.f;
        for (int i = 0; i < LD; ++i) a += sm.loc[i] * w_local[i*PD + p];
        sm.basev[p] = a;
    } else if (tid >= 128 && tid < 192){
        int p = tid - 128; float a = 0.f;
        for (int i = 0; i < LD; ++i) a += sm.loc[i] * w_gate[i*PD + p];
        sm.gatevv[p] = gelu_f(a);
    } else if (tid == 255){
        float nx=sm.posall3[0], ny=sm.posall3[1], nz=sm.posall3[2];
        float cax=sm.posall3[3], cay=sm.posall3[4], caz=sm.posall3[5];
        float cx=sm.posall3[6], cy=sm.posall3[7], cz=sm.posall3[8];
        float v1x=cx-cax, v1y=cy-cay, v1z=cz-caz;
        float r = 1.0f/sqrtf(v1x*v1x + v1y*v1y + v1z*v1z + 1e-6f);
        float e1x=v1x*r, e1y=v1y*r, e1z=v1z*r;
        float v2x=nx-cax, v2y=ny-cay, v2z=nz-caz;
        float dp = e1x*v2x + e1y*v2y + e1z*v2z;
        float u2x=v2x-e1x*dp, u2y=v2y-e1y*dp, u2z=v2z-e1z*dp;
        r = 1.0f/sqrtf(u2x*u2x + u2y*u2y + u2z*u2z + 1e-6f);
        float e2x=u2x*r, e2y=u2y*r, e2z=u2z*r;
        float e3x=e1y*e2z-e1z*e2y, e3y=e1z*e2x-e1x*e2z, e3z=e1x*e2y-e1y*e2x;
        sm.rot[0]=e1x; sm.rot[1]=e2x; sm.rot[2]=e3x;
        sm.rot[3]=e1y; sm.rot[4]=e2y; sm.rot[5]=e3y;
        sm.rot[6]=e1z; sm.rot[7]=e2z; sm.rot[8]=e3z;
        sm.ca3[0]=cax; sm.ca3[1]=cay; sm.ca3[2]=caz;
    } else if (tid == 254){
        float c = 0.f;
        for (int s = 0; s < SS; ++s) c += sm.maskf[s];
        sm.cnt = c;
    }
    __syncthreads();
    if (tid < 33){
        int k = tid / 3, i2 = tid - k*3;
        sm.posall3[(A0C + k)*3 + i2] =
            sm.rot[i2*3+0]*sm.pl[k*3+0] + sm.rot[i2*3+1]*sm.pl[k*3+1] +
            sm.rot[i2*3+2]*sm.pl[k*3+2] + sm.ca3[i2];
    }
    __syncthreads();   // posall3 visible to all waves

    // own-row smol coords in REGISTERS (no LDS handoff)
    const float px0 = g_spos[(n*SS + sl0)*3 + 0];
    const float py0 = g_spos[(n*SS + sl0)*3 + 1];
    const float pz0 = g_spos[(n*SS + sl0)*3 + 2];
    const float px1 = g_spos[(n*SS + sl1)*3 + 0];
    const float py1 = g_spos[(n*SS + sl1)*3 + 1];
    const float pz1 = g_spos[(n*SS + sl1)*3 + 2];

    // prefetch slice 0 (wsD k 0..63) — latency hides under dist compute
    u32x4 pfa, pfb;
    loadStage(wsD, 256, tid, pfa, pfb);

    // dist for this wave's 32 rows (cross-lane reads only after next barrier)
    #pragma unroll
    for (int aa = 0; aa < 4; ++aa){
        int a = g*4 + aa;
        float ax = sm.posall3[a*3+0], ay = sm.posall3[a*3+1], az = sm.posall3[a*3+2];
        float rx0 = px0-ax, ry0 = py0-ay, rz0 = pz0-az;
        sm.dist[sl0*17 + a] = sqrtf(rx0*rx0 + ry0*ry0 + rz0*rz0 + 1e-6f);
        float rx1 = px1-ax, ry1 = py1-ay, rz1 = pz1-az;
        sm.dist[sl1*17 + a] = sqrtf(rx1*rx1 + ry1*ry1 + rz1*rz1 + 1e-6f);
    }

    const float b0c = (float)((g&1) * 8) * 1.28119724f;

    // ---- pair GEMM: dist-RBF (K=256), slices prefetched one ahead ----
    f32x4 accP0 = {0.f,0.f,0.f,0.f}, accP1 = accP0, accP2 = accP0, accP3 = accP0;  // tile 0
    f32x4 accQ0 = accP0, accQ1 = accP0, accQ2 = accP0, accQ3 = accP0;              // tile 1

    for (int h = 0; h < 4; ++h){
        pubStage(pfa, pfb, sm.wbuf, tid);
        if (h < 3) loadStage(wsD + (h+1)*64, 256, tid, pfa, pfb);
        else       loadStage(wsDir, 64, tid, pfa, pfb);
        #pragma unroll
        for (int kkl = 0; kkl < 2; ++kkl){
            const int kk = h*2 + kkl;
            bf16x8 av0, av1;
            RBF_FRAG(av0, sl0);
            RBF_FRAG(av1, sl1);
            const unsigned short* bb = &sm.wbuf[cB*72 + kkl*32 + g*8];
            bf16x8 B0 = *(const bf16x8*)(bb +  0*72);
            bf16x8 B1 = *(const bf16x8*)(bb + 16*72);
            bf16x8 B2 = *(const bf16x8*)(bb + 32*72);
            bf16x8 B3 = *(const bf16x8*)(bb + 48*72);
            accP0 = MFMA(av0, B0, accP0);  accQ0 = MFMA(av1, B0, accQ0);
            accP1 = MFMA(av0, B1, accP1);  accQ1 = MFMA(av1, B1, accQ1);
            accP2 = MFMA(av0, B2, accP2);  accQ2 = MFMA(av1, B2, accQ2);
            accP3 = MFMA(av0, B3, accP3);  accQ3 = MFMA(av1, B3, accQ3);
        }
    }

    // ---- + directions @ w_dir (K=48 pad 64) ----
    pubStage(pfa, pfb, sm.wbuf, tid);                 // wsDir
    loadStage(wsM1, 64, tid, pfa, pfb);               // prefetch M1a
    #pragma unroll
    for (int kk = 0; kk < 2; ++kk){
        int k0 = kk*32 + g*8;
        unsigned int a0w0 = pk2bf(dirv2(sm,px0,py0,pz0,sl0,k0+0), dirv2(sm,px0,py0,pz0,sl0,k0+1));
        unsigned int a0w1 = pk2bf(dirv2(sm,px0,py0,pz0,sl0,k0+2), dirv2(sm,px0,py0,pz0,sl0,k0+3));
        unsigned int a0w2 = pk2bf(dirv2(sm,px0,py0,pz0,sl0,k0+4), dirv2(sm,px0,py0,pz0,sl0,k0+5));
        unsigned int a0w3 = pk2bf(dirv2(sm,px0,py0,pz0,sl0,k0+6), dirv2(sm,px0,py0,pz0,sl0,k0+7));
        bf16x8 av0 = __builtin_bit_cast(bf16x8, (u32x4){a0w0,a0w1,a0w2,a0w3});
        unsigned int a1w0 = pk2bf(dirv2(sm,px1,py1,pz1,sl1,k0+0), dirv2(sm,px1,py1,pz1,sl1,k0+1));
        unsigned int a1w1 = pk2bf(dirv2(sm,px1,py1,pz1,sl1,k0+2), dirv2(sm,px1,py1,pz1,sl1,k0+3));
        unsigned int a1w2 = pk2bf(dirv2(sm,px1,py1,pz1,sl1,k0+4), dirv2(sm,px1,py1,pz1,sl1,k0+5));
        unsigned int a1w3 = pk2bf(dirv2(sm,px1,py1,pz1,sl1,k0+6), dirv2(sm,px1,py1,pz1,sl1,k0+7));
        bf16x8 av1 = __builtin_bit_cast(bf16x8, (u32x4){a1w0,a1w1,a1w2,a1w3});
        const unsigned short* bb = &sm.wbuf[cB*72 + k0];
        bf16x8 B0 = *(const bf16x8*)(bb +  0*72);
        bf16x8 B1 = *(const bf16x8*)(bb + 16*72);
        bf16x8 B2 = *(const bf16x8*)(bb + 32*72);
        bf16x8 B3 = *(const bf16x8*)(bb + 48*72);
        accP0 = MFMA(av0, B0, accP0);  accQ0 = MFMA(av1, B0, accQ0);
        accP1 = MFMA(av0, B1, accP1);  accQ1 = MFMA(av1, B1, accQ1);
        accP2 = MFMA(av0, B2, accP2);  accQ2 = MFMA(av1, B2, accQ2);
        accP3 = MFMA(av0, B3, accP3);  accQ3 = MFMA(av1, B3, accQ3);
    }

    // ---- epilogue: + base + wtype, LayerNorm, bf16 stores to pairT ----
    #pragma unroll
    for (int t = 0; t < 2; ++t){
        #pragma unroll
        for (int r = 0; r < 4; ++r){
            int slr = 32*wv + 16*t + g*4 + r;
            int ty  = sm.typef[slr];
            float a0 = (t==0 ? accP0[r] : accQ0[r]);
            float a1 = (t==0 ? accP1[r] : accQ1[r]);
            float a2 = (t==0 ? accP2[r] : accQ2[r]);
            float a3 = (t==0 ? accP3[r] : accQ3[r]);
            float v0 = a0 + sm.basev[cB +  0] + sm.wtypef[ty*PD + cB +  0];
            float v1 = a1 + sm.basev[cB + 16] + sm.wtypef[ty*PD + cB + 16];
            float v2 = a2 + sm.basev[cB + 32] + sm.wtypef[ty*PD + cB + 32];
            float v3 = a3 + sm.basev[cB + 48] + sm.wtypef[ty*PD + cB + 48];
            float ssum = v0+v1+v2+v3;
            ssum += __shfl_xor(ssum,1); ssum += __shfl_xor(ssum,2);
            ssum += __shfl_xor(ssum,4); ssum += __shfl_xor(ssum,8);
            float mu = ssum * (1.0f/64.0f);
            float d0=v0-mu, d1=v1-mu, d2=v2-mu, d3=v3-mu;
            float sq = d0*d0+d1*d1+d2*d2+d3*d3;
            sq += __shfl_xor(sq,1); sq += __shfl_xor(sq,2);
            sq += __shfl_xor(sq,4); sq += __shfl_xor(sq,8);
            float inv = 1.0f / sqrtf(sq*(1.0f/64.0f) + 1e-5f);
            unsigned short* pr = &sm.pairT[slr*72];
            pr[cB +  0] = f2bfhu(d0*inv*sm.lnsc[cB +  0] + sm.lnof[cB +  0]);
            pr[cB + 16] = f2bfhu(d1*inv*sm.lnsc[cB + 16] + sm.lnof[cB + 16]);
            pr[cB + 32] = f2bfhu(d2*inv*sm.lnsc[cB + 32] + sm.lnof[cB + 32]);
            pr[cB + 48] = f2bfhu(d3*inv*sm.lnsc[cB + 48] + sm.lnof[cB + 48]);
        }
    }

    // ==== MLP1/MLP2 interleaved in k-halves (r15 schedule, prefetched) ====
    f32x4 accO0 = {0.f,0.f,0.f,0.f}, accO1 = accO0, accO2 = accO0, accO3 = accO0;  // tile 0
    f32x4 accN0 = accO0, accN1 = accO0, accN2 = accO0, accN3 = accO0;              // tile 1

    // ---- MLP1 half a (hidden cols 0..63) ----
    f32x4 accH0 = {0.f,0.f,0.f,0.f}, accH1 = accH0, accH2 = accH0, accH3 = accH0;
    f32x4 accI0 = accH0, accI1 = accH0, accI2 = accH0, accI3 = accH0;
    pubStage(pfa, pfb, sm.wbuf, tid);                 // M1a; retires dist, publishes pairT
    loadStage(wsM2, 128, tid, pfa, pfb);              // prefetch M2a
    #pragma unroll
    for (int kk = 0; kk < 2; ++kk){
        bf16x8 a0 = *(const bf16x8*)&sm.pairT[sl0*72 + kk*32 + g*8];
        bf16x8 a1 = *(const bf16x8*)&sm.pairT[sl1*72 + kk*32 + g*8];
        const unsigned short* bb = &sm.wbuf[cB*72 + kk*32 + g*8];
        bf16x8 B0 = *(const bf16x8*)(bb + 0*16*72);
        bf16x8 B1 = *(const bf16x8*)(bb + 1*16*72);
        bf16x8 B2 = *(const bf16x8*)(bb + 2*16*72);
        bf16x8 B3 = *(const bf16x8*)(bb + 3*16*72);
        accH0 = MFMA(a0, B0, accH0);  accI0 = MFMA(a1, B0, accI0);
        accH1 = MFMA(a0, B1, accH1);  accI1 = MFMA(a1, B1, accI1);
        accH2 = MFMA(a0, B2, accH2);  accI2 = MFMA(a1, B2, accI2);
        accH3 = MFMA(a0, B3, accH3);  accI3 = MFMA(a1, B3, accI3);
    }
    #pragma unroll
    for (int r = 0; r < 4; ++r){
        int slr0 = 32*wv + g*4 + r;
        unsigned short* hr0 = &sm.hidT[slr0*72];
        hr0[cB + 0*16] = f2bfhu(gelu_f(accH0[r] + sm.b1v[cB + 0*16]));
        hr0[cB + 1*16] = f2bfhu(gelu_f(accH1[r] + sm.b1v[cB + 1*16]));
        hr0[cB + 2*16] = f2bfhu(gelu_f(accH2[r] + sm.b1v[cB + 2*16]));
        hr0[cB + 3*16] = f2bfhu(gelu_f(accH3[r] + sm.b1v[cB + 3*16]));
        unsigned short* hr1 = &sm.hidT[(slr0+16)*72];
        hr1[cB + 0*16] = f2bfhu(gelu_f(accI0[r] + sm.b1v[cB + 0*16]));
        hr1[cB + 1*16] = f2bfhu(gelu_f(accI1[r] + sm.b1v[cB + 1*16]));
        hr1[cB + 2*16] = f2bfhu(gelu_f(accI2[r] + sm.b1v[cB + 2*16]));
        hr1[cB + 3*16] = f2bfhu(gelu_f(accI3[r] + sm.b1v[cB + 3*16]));
    }

    // ---- MLP2 k-half 0 (k = 0..63) ----
    pubStage(pfa, pfb, sm.wbuf, tid);                 // M2a; publishes hidT half a
    loadStage(wsM1 + 64*64, 64, tid, pfa, pfb);       // prefetch M1b
    #pragma unroll
    for (int kkl = 0; kkl < 2; ++kkl){
        bf16x8 a0 = *(const bf16x8*)&sm.hidT[sl0*72 + kkl*32 + g*8];
        bf16x8 a1 = *(const bf16x8*)&sm.hidT[sl1*72 + kkl*32 + g*8];
        const unsigned short* bb = &sm.wbuf[cB*72 + kkl*32 + g*8];
        bf16x8 B0 = *(const bf16x8*)(bb + 0*16*72);
        bf16x8 B1 = *(const bf16x8*)(bb + 1*16*72);
        bf16x8 B2 = *(const bf16x8*)(bb + 2*16*72);
        bf16x8 B3 = *(const bf16x8*)(bb + 3*16*72);
        accO0 = MFMA(a0, B0, accO0);  accN0 = MFMA(a1, B0, accN0);
        accO1 = MFMA(a0, B1, accO1);  accN1 = MFMA(a1, B1, accN1);
        accO2 = MFMA(a0, B2, accO2);  accN2 = MFMA(a1, B2, accN2);
        accO3 = MFMA(a0, B3, accO3);  accN3 = MFMA(a1, B3, accN3);
    }

    // ---- MLP1 half b (hidden cols 64..127) ----
    f32x4 accH4 = {0.f,0.f,0.f,0.f}, accH5 = accH4, accH6 = accH4, accH7 = accH4;
    f32x4 accI4 = accH4, accI5 = accH4, accI6 = accH4, accI7 = accH4;
    pubStage(pfa, pfb, sm.wbuf, tid);                 // M1b; retires hidT-half-a reads
    loadStage(wsM2 + 64, 128, tid, pfa, pfb);         // prefetch M2b
    #pragma unroll
    for (int kk = 0; kk < 2; ++kk){
        bf16x8 a0 = *(const bf16x8*)&sm.pairT[sl0*72 + kk*32 + g*8];
        bf16x8 a1 = *(const bf16x8*)&sm.pairT[sl1*72 + kk*32 + g*8];
        const unsigned short* bb = &sm.wbuf[cB*72 + kk*32 + g*8];
        bf16x8 B0 = *(const bf16x8*)(bb + 0*16*72);
        bf16x8 B1 = *(const bf16x8*)(bb + 1*16*72);
        bf16x8 B2 = *(const bf16x8*)(bb + 2*16*72);
        bf16x8 B3 = *(const bf16x8*)(bb + 3*16*72);
        accH4 = MFMA(a0, B0, accH4);  accI4 = MFMA(a1, B0, accI4);
        accH5 = MFMA(a0, B1, accH5);  accI5 = MFMA(a1, B1, accI5);
        accH6 = MFMA(a0, B2, accH6);  accI6 = MFMA(a1, B2, accI6);
        accH7 = MFMA(a0, B3, accH7);  accI7 = MFMA(a1, B3, accI7);
    }
    #pragma unroll
    for (int r = 0; r < 4; ++r){
        int slr0 = 32*wv + g*4 + r;
        unsigned short* hr0 = &sm.hidT[slr0*72];
        hr0[cB + 0*16] = f2bfhu(gelu_f(accH4[r] + sm.b1v[cB + 4*16]));
        hr0[cB + 1*16] = f2bfhu(gelu_f(accH5[r] + sm.b1v[cB + 5*16]));
        hr0[cB + 2*16] = f2bfhu(gelu_f(accH6[r] + sm.b1v[cB + 6*16]));
        hr0[cB + 3*16] = f2bfhu(gelu_f(accH7[r] + sm.b1v[cB + 7*16]));
        unsigned short* hr1 = &sm.hidT[(slr0+16)*72];
        hr1[cB + 0*16] = f2bfhu(gelu_f(accI4[r] + sm.b1v[cB + 4*16]));
        hr1[cB + 1*16] = f2bfhu(gelu_f(accI5[r] + sm.b1v[cB + 5*16]));
        hr1[cB + 2*16] = f2bfhu(gelu_f(accI6[r] + sm.b1v[cB + 6*16]));
        hr1[cB + 3*16] = f2bfhu(gelu_f(accI7[r] + sm.b1v[cB + 7*16]));
    }

    // ---- MLP2 k-half 1 (k = 64..127) ----
    pubStage(pfa, pfb, sm.wbuf, tid);                 // M2b; publishes hidT half b
    #pragma unroll
    for (int kkl = 0; kkl < 2; ++kkl){
        bf16x8 a0 = *(const bf16x8*)&sm.hidT[sl0*72 + kkl*32 + g*8];
        bf16x8 a1 = *(const bf16x8*)&sm.hidT[sl1*72 + kkl*32 + g*8];
        const unsigned short* bb = &sm.wbuf[cB*72 + kkl*32 + g*8];
        bf16x8 B0 = *(const bf16x8*)(bb + 0*16*72);
        bf16x8 B1 = *(const bf16x8*)(bb + 1*16*72);
        bf16x8 B2 = *(const bf16x8*)(bb + 2*16*72);
        bf16x8 B3 = *(const bf16x8*)(bb + 3*16*72);
        accO0 = MFMA(a0, B0, accO0);  accN0 = MFMA(a1, B0, accN0);
        accO1 = MFMA(a0, B1, accO1);  accN1 = MFMA(a1, B1, accN1);
        accO2 = MFMA(a0, B2, accO2);  accN2 = MFMA(a1, B2, accN2);
        accO3 = MFMA(a0, B3, accO3);  accN3 = MFMA(a1, B3, accN3);
    }

    float pooled0 = 0.f, pooled1 = 0.f, pooled2 = 0.f, pooled3 = 0.f;
    #pragma unroll
    for (int r = 0; r < 4; ++r){
        float m0f = sm.maskf[32*wv + g*4 + r];
        float m1f = sm.maskf[32*wv + 16 + g*4 + r];
        pooled0 += m0f * accO0[r] + m1f * accN0[r];
        pooled1 += m0f * accO1[r] + m1f * accN1[r];
        pooled2 += m0f * accO2[r] + m1f * accN2[r];
        pooled3 += m0f * accO3[r] + m1f * accN3[r];
    }

    // ---- reduce pooled: across g-groups (same col), then across waves ----
    pooled0 += __shfl_xor(pooled0,16); pooled0 += __shfl_xor(pooled0,32);
    pooled1 += __shfl_xor(pooled1,16); pooled1 += __shfl_xor(pooled1,32);
    pooled2 += __shfl_xor(pooled2,16); pooled2 += __shfl_xor(pooled2,32);
    pooled3 += __shfl_xor(pooled3,16); pooled3 += __shfl_xor(pooled3,32);
    if (g == 0){
        sm.red[wv*PD + cB +  0] = pooled0;
        sm.red[wv*PD + cB + 16] = pooled1;
        sm.red[wv*PD + cB + 32] = pooled2;
        sm.red[wv*PD + cB + 48] = pooled3;
    }
    __syncthreads();
    if (tid < PD){
        float v = sm.red[tid] + sm.red[PD + tid] + sm.red[2*PD + tid] + sm.red[3*PD + tid];
        float mc = fmaxf(sm.cnt, 1.0f);
        v = (v + sm.cnt * sm.b2v[tid]) / mc;        // adds b2 exactly like ref (0 if cnt==0)
        sm.fin[tid] = sm.gatevv[tid] * v;
    }
    __syncthreads();
    {
        float a = 0.f;
        #pragma unroll 4
        for (int p = 0; p < PD; ++p) a += sm.fin[p] * w_out[p*LD + tid];
        g_out[n*LD + tid] = a;
    }
}

extern "C" void kernel_launch(void* const* d_in, const int* in_sizes, int n_in,
                              void* d_out, int out_size, void* d_ws, size_t ws_size,
                              hipStream_t stream)
{
    (void)in_sizes; (void)n_in; (void)out_size; (void)ws_size;
    const float* g_local   = (const float*)d_in[0];
    const float* g_pos     = (const float*)d_in[1];
    const int*   g_type    = (const int*)  d_in[2];
    const float* g_spos    = (const float*)d_in[3];
    const int*   g_mask    = (const int*)  d_in[4];
    const float* w_points  = (const float*)d_in[5];
    const float* w_type    = (const float*)d_in[6];
    const float* w_local   = (const float*)d_in[7];
    const float* w_dir     = (const float*)d_in[8];
    const float* w_dist    = (const float*)d_in[9];
    const float* ln_scale  = (const float*)d_in[10];
    const float* ln_offset = (const float*)d_in[11];
    const float* w_mlp1    = (const float*)d_in[12];
    const float* b_mlp1    = (const float*)d_in[13];
    const float* w_mlp2    = (const float*)d_in[14];
    const float* b_mlp2    = (const float*)d_in[15];
    const float* w_gate    = (const float*)d_in[16];
    const float* w_out     = (const float*)d_in[17];

    unsigned short* ws = (unsigned short*)d_ws;   // 73728 B

    smol_prep<<<dim3(144), dim3(256), 0, stream>>>(w_dist, w_dir, w_mlp1, w_mlp2, ws);

    smol_fused<<<dim3(NRES), dim3(256), 0, stream>>>(
        g_local, g_pos, g_type, g_spos, g_mask,
        w_points, w_local, w_type, ln_scale, ln_offset,
        b_mlp1, b_mlp2, w_gate, w_out, ws, (float*)d_out);
}

// Round 18
// 132.617 us; speedup vs baseline: 2.1420x; 1.0451x over previous
//
#include <hip/hip_runtime.h>
#include <math.h>

#define NRES 4096
#define SS   128
#define A0C  5
#define ATOT 16
#define LD   256
#define PD   64
#define HD   128

typedef __attribute__((ext_vector_type(8))) short bf16x8;
typedef __attribute__((ext_vector_type(4))) float f32x4;
typedef __attribute__((ext_vector_type(4))) unsigned int u32x4;

__device__ __forceinline__ unsigned short f2bf(float x){
    unsigned int u = __builtin_bit_cast(unsigned int, x);
    unsigned int r = u + 0x7FFFu + ((u >> 16) & 1u);   // RNE to bf16 (prep only)
    return (unsigned short)(r >> 16);
}
__device__ __forceinline__ unsigned short f2bfhu(float x){
    return (unsigned short)((__builtin_bit_cast(unsigned int, x) + 0x8000u) >> 16);
}
__device__ __forceinline__ unsigned int pk2bf(float lo, float hi){
    unsigned int a = __builtin_bit_cast(unsigned int, lo) + 0x8000u;
    unsigned int b = __builtin_bit_cast(unsigned int, hi) + 0x8000u;
    return __builtin_amdgcn_perm(b, a, 0x07060302u);
}
// r18: exp2-folded tanh-gelu (log2e folded into the constant), rcp for divide
__device__ __forceinline__ float gelu_f(float x){
    float e = __builtin_amdgcn_exp2f(-2.3022082f * x * (1.0f + 0.044715f * x * x));
    return x * __builtin_amdgcn_rcpf(1.0f + e);
}
__device__ __forceinline__ f32x4 MFMA(bf16x8 a, bf16x8 b, f32x4 c){
    return __builtin_amdgcn_mfma_f32_16x16x32_bf16(a, b, c, 0, 0, 0);
}

// ---------------- prep: transpose+convert weights to bf16 in d_ws ----------------
// layout (ushort elements)  [identical to r5..r17 — 73728 B total]:
//   [0)      wsD   [64 n][256 k]   (w_dist^T)
//   [16384)  wsDir [64 n][64 k]    (w_dir^T, k>=48 zero)
//   [20480)  wsM1  [128 n][64 k]   (w_mlp1^T)
//   [28672)  wsM2  [64 n][128 k]   (w_mlp2^T)
__global__ void smol_prep(const float* __restrict__ wdist, const float* __restrict__ wdir,
                          const float* __restrict__ wm1,  const float* __restrict__ wm2,
                          unsigned short* __restrict__ ws)
{
    int i = blockIdx.x * 256 + threadIdx.x;
    if (i < 16384){
        int nn = i >> 8, k = i & 255;
        ws[i] = f2bf(wdist[k*64 + nn]);
    } else if (i < 20480){
        int j = i - 16384; int nn = j >> 6, k = j & 63;
        ws[i] = (k < 48) ? f2bf(wdir[k*64 + nn]) : (unsigned short)0;
    } else if (i < 28672){
        int j = i - 20480; int nn = j >> 6, k = j & 63;
        ws[i] = f2bf(wm1[k*128 + nn]);
    } else if (i < 36864){
        int j = i - 28672; int nn = j >> 7, k = j & 127;
        ws[i] = f2bf(wm2[k*64 + nn]);
    }
}

// ---------------- main fused kernel ----------------
// r18 = r17 schedule EXACTLY + VALU/LDS polish:
//  - gelu via exp2 (folded log2e), LN via v_rsq_f32
//  - loop-invariant LDS scalars (lnsc/lnof/basev, b1v) hoisted to registers
//    (intervening LDS stores defeat compiler aliasing -> redundant ds_read_b32)
struct __align__(16) SMem {
    unsigned short wbuf[64*72];     // 9216 B staged weight slice
    union {
        float  dist[128*17];        // live until dir phase
        unsigned short hidT[128*72];// live in MLP1/MLP2 (after barrier)
    };
    unsigned short pairT[128*72];   // bf16 [s][k<=64], stride 72
    float  loc[LD];
    float  posall3[ATOT*3];
    float  pl[33];
    float  rot[9];
    float  ca3[3];
    float  wtypef[7*PD];
    float  basev[PD];
    float  gatevv[PD];
    float  lnsc[PD], lnof[PD];
    float  b1v[HD], b2v[PD];
    int    typef[SS];
    float  maskf[SS];
    float  red[4*PD];
    float  fin[PD];
    float  cnt;
};

__device__ __forceinline__ float dirv2(const SMem& sm, float px, float py, float pz,
                                       int sl, int k){
    int kc = (k < 48) ? k : 47;
    int a = (kc * 21846) >> 16;     // kc/3
    int c = kc - 3*a;
    float pc = (c == 0) ? px : ((c == 1) ? py : pz);
    float e = (pc - sm.posall3[a*3+c]) * __builtin_amdgcn_rcpf(sm.dist[sl*17 + a]);
    return (k < 48) ? e : 0.0f;
}

// issue a slice's global loads into registers (no barrier, no LDS).
__device__ __forceinline__ void loadStage(const unsigned short* __restrict__ src, int stride,
                                          int tid, u32x4& a, u32x4& b){
    int r = tid >> 3, s = (tid & 7) * 8;
    a = *(const u32x4*)&src[r*stride + s];
    b = *(const u32x4*)&src[(r+32)*stride + s];
}
// publish a prefetched slice: barrier -> 2x ds_write_b128 -> barrier.
__device__ __forceinline__ void pubStage(u32x4 a, u32x4 b, unsigned short* dst, int tid){
    __syncthreads();
    int r = tid >> 3, s = (tid & 7) * 8;
    *(u32x4*)&dst[r*72 + s]      = a;
    *(u32x4*)&dst[(r+32)*72 + s] = b;
    __syncthreads();
}

// RBF A-fragment: val_j = exp2(-(d*A - cA_j)^2), A = sqrt(log2e)/0.75
#define RBF_FRAG(av, sl) do {                                               \
    float dA_ = sm.dist[(sl)*17 + 2*kk + (g>>1)] * 1.60149654f;             \
    float z0_ = dA_ - (b0c + 0.00000000f);                                  \
    float z1_ = dA_ - (b0c + 1.28119724f);                                  \
    float z2_ = dA_ - (b0c + 2.56239447f);                                  \
    float z3_ = dA_ - (b0c + 3.84359171f);                                  \
    float z4_ = dA_ - (b0c + 5.12478894f);                                  \
    float z5_ = dA_ - (b0c + 6.40598618f);                                  \
    float z6_ = dA_ - (b0c + 7.68718342f);                                  \
    float z7_ = dA_ - (b0c + 8.96838065f);                                  \
    unsigned int w0_ = pk2bf(__builtin_amdgcn_exp2f((-z0_)*z0_),            \
                             __builtin_amdgcn_exp2f((-z1_)*z1_));           \
    unsigned int w1_ = pk2bf(__builtin_amdgcn_exp2f((-z2_)*z2_),            \
                             __builtin_amdgcn_exp2f((-z3_)*z3_));           \
    unsigned int w2_ = pk2bf(__builtin_amdgcn_exp2f((-z4_)*z4_),            \
                             __builtin_amdgcn_exp2f((-z5_)*z5_));           \
    unsigned int w3_ = pk2bf(__builtin_amdgcn_exp2f((-z6_)*z6_),            \
                             __builtin_amdgcn_exp2f((-z7_)*z7_));           \
    av = __builtin_bit_cast(bf16x8, (u32x4){w0_, w1_, w2_, w3_});           \
} while(0)

__global__ __launch_bounds__(256, 3)
void smol_fused(const float* __restrict__ g_local,
                const float* __restrict__ g_pos,
                const int*   __restrict__ g_type,
                const float* __restrict__ g_spos,
                const int*   __restrict__ g_mask,
                const float* __restrict__ w_points,
                const float* __restrict__ w_local,
                const float* __restrict__ w_type,
                const float* __restrict__ ln_scale,
                const float* __restrict__ ln_offset,
                const float* __restrict__ b_mlp1,
                const float* __restrict__ b_mlp2,
                const float* __restrict__ w_gate,
                const float* __restrict__ w_out,
                const unsigned short* __restrict__ ws,
                float* __restrict__ g_out)
{
    __shared__ SMem sm;
    const int n    = blockIdx.x;
    const int tid  = threadIdx.x;
    const int wv   = tid >> 6;        // wave 0..3 : owns rows 32wv..32wv+31
    const int lane = tid & 63;
    const int cB   = lane & 15;       // A-row / B-col selector
    const int g    = lane >> 4;       // k-subgroup 0..3
    const int sl0  = 32*wv + cB;      // tile-0 A row
    const int sl1  = sl0 + 16;        // tile-1 A row

    const unsigned short* wsD   = ws;
    const unsigned short* wsDir = ws + 16384;
    const unsigned short* wsM1  = ws + 20480;
    const unsigned short* wsM2  = ws + 28672;

    // ---------- stage per-n data + small weights ----------
    sm.loc[tid] = g_local[n*LD + tid];
    sm.wtypef[tid] = w_type[tid];
    if (tid < 7*PD - 256) sm.wtypef[256 + tid] = w_type[256 + tid];
    if (tid < PD){ sm.lnsc[tid] = ln_scale[tid]; sm.lnof[tid] = ln_offset[tid]; sm.b2v[tid] = b_mlp2[tid]; }
    if (tid < HD) sm.b1v[tid] = b_mlp1[tid];
    if (tid < SS){ sm.typef[tid] = g_type[n*SS + tid];
                   sm.maskf[tid] = (g_mask[n*SS + tid] != 0) ? 1.0f : 0.0f; }
    if (tid >= 128 && tid < 128 + A0C*3) sm.posall3[tid-128] = g_pos[n*A0C*3 + (tid-128)];
    __syncthreads();

    // ---------- per-n precompute ----------
    if (tid < 33){
        float a = 0.f;
        for (int i = 0; i < LD; ++i) a += sm.loc[i] * w_points[i*33 + tid];
        sm.pl[tid] = a;
    } else if (tid >= 64 && tid < 128){
        int p = tid - 64; float a = 0.f;
        for (int i = 0; i < LD; ++i) a += sm.loc[i] * w_local[i*PD + p];
        sm.basev[p] = a;
    } else if (tid >= 128 && tid < 192){
        int p = tid - 128; float a = 0.f;
        for (int i = 0; i < LD; ++i) a += sm.loc[i] * w_gate[i*PD + p];
        sm.gatevv[p] = gelu_f(a);
    } else if (tid == 255){
        float nx=sm.posall3[0], ny=sm.posall3[1], nz=sm.posall3[2];
        float cax=sm.posall3[3], cay=sm.posall3[4], caz=sm.posall3[5];
        float cx=sm.posall3[6], cy=sm.posall3[7], cz=sm.posall3[8];
        float v1x=cx-cax, v1y=cy-cay, v1z=cz-caz;
        float r = 1.0f/sqrtf(v1x*v1x + v1y*v1y + v1z*v1z + 1e-6f);
        float e1x=v1x*r, e1y=v1y*r, e1z=v1z*r;
        float v2x=nx-cax, v2y=ny-cay, v2z=nz-caz;
        float dp = e1x*v2x + e1y*v2y + e1z*v2z;
        float u2x=v2x-e1x*dp, u2y=v2y-e1y*dp, u2z=v2z-e1z*dp;
        r = 1.0f/sqrtf(u2x*u2x + u2y*u2y + u2z*u2z + 1e-6f);
        float e2x=u2x*r, e2y=u2y*r, e2z=u2z*r;
        float e3x=e1y*e2z-e1z*e2y, e3y=e1z*e2x-e1x*e2z, e3z=e1x*e2y-e1y*e2x;
        sm.rot[0]=e1x; sm.rot[1]=e2x; sm.rot[2]=e3x;
        sm.rot[3]=e1y; sm.rot[4]=e2y; sm.rot[5]=e3y;
        sm.rot[6]=e1z; sm.rot[7]=e2z; sm.rot[8]=e3z;
        sm.ca3[0]=cax; sm.ca3[1]=cay; sm.ca3[2]=caz;
    } else if (tid == 254){
        float c = 0.f;
        for (int s = 0; s < SS; ++s) c += sm.maskf[s];
        sm.cnt = c;
    }
    __syncthreads();
    if (tid < 33){
        int k = tid / 3, i2 = tid - k*3;
        sm.posall3[(A0C + k)*3 + i2] =
            sm.rot[i2*3+0]*sm.pl[k*3+0] + sm.rot[i2*3+1]*sm.pl[k*3+1] +
            sm.rot[i2*3+2]*sm.pl[k*3+2] + sm.ca3[i2];
    }
    __syncthreads();   // posall3 visible to all waves

    // own-row smol coords in REGISTERS (no LDS handoff)
    const float px0 = g_spos[(n*SS + sl0)*3 + 0];
    const float py0 = g_spos[(n*SS + sl0)*3 + 1];
    const float pz0 = g_spos[(n*SS + sl0)*3 + 2];
    const float px1 = g_spos[(n*SS + sl1)*3 + 0];
    const float py1 = g_spos[(n*SS + sl1)*3 + 1];
    const float pz1 = g_spos[(n*SS + sl1)*3 + 2];

    // prefetch slice 0 (wsD k 0..63)
    u32x4 pfa, pfb;
    loadStage(wsD, 256, tid, pfa, pfb);

    // dist for this wave's 32 rows
    #pragma unroll
    for (int aa = 0; aa < 4; ++aa){
        int a = g*4 + aa;
        float ax = sm.posall3[a*3+0], ay = sm.posall3[a*3+1], az = sm.posall3[a*3+2];
        float rx0 = px0-ax, ry0 = py0-ay, rz0 = pz0-az;
        sm.dist[sl0*17 + a] = sqrtf(rx0*rx0 + ry0*ry0 + rz0*rz0 + 1e-6f);
        float rx1 = px1-ax, ry1 = py1-ay, rz1 = pz1-az;
        sm.dist[sl1*17 + a] = sqrtf(rx1*rx1 + ry1*ry1 + rz1*rz1 + 1e-6f);
    }

    // hoisted per-lane column constants (r18)
    const float lnS0 = sm.lnsc[cB+ 0], lnS1 = sm.lnsc[cB+16],
                lnS2 = sm.lnsc[cB+32], lnS3 = sm.lnsc[cB+48];
    const float lnO0 = sm.lnof[cB+ 0], lnO1 = sm.lnof[cB+16],
                lnO2 = sm.lnof[cB+32], lnO3 = sm.lnof[cB+48];
    const float bs0 = sm.basev[cB+ 0], bs1 = sm.basev[cB+16],
                bs2 = sm.basev[cB+32], bs3 = sm.basev[cB+48];
    const float b1a0 = sm.b1v[cB+0*16], b1a1 = sm.b1v[cB+1*16],
                b1a2 = sm.b1v[cB+2*16], b1a3 = sm.b1v[cB+3*16];
    const float b1b0 = sm.b1v[cB+4*16], b1b1 = sm.b1v[cB+5*16],
                b1b2 = sm.b1v[cB+6*16], b1b3 = sm.b1v[cB+7*16];

    const float b0c = (float)((g&1) * 8) * 1.28119724f;

    // ---- pair GEMM: dist-RBF (K=256), slices prefetched one ahead ----
    f32x4 accP0 = {0.f,0.f,0.f,0.f}, accP1 = accP0, accP2 = accP0, accP3 = accP0;  // tile 0
    f32x4 accQ0 = accP0, accQ1 = accP0, accQ2 = accP0, accQ3 = accP0;              // tile 1

    for (int h = 0; h < 4; ++h){
        pubStage(pfa, pfb, sm.wbuf, tid);
        if (h < 3) loadStage(wsD + (h+1)*64, 256, tid, pfa, pfb);
        else       loadStage(wsDir, 64, tid, pfa, pfb);
        #pragma unroll
        for (int kkl = 0; kkl < 2; ++kkl){
            const int kk = h*2 + kkl;
            bf16x8 av0, av1;
            RBF_FRAG(av0, sl0);
            RBF_FRAG(av1, sl1);
            const unsigned short* bb = &sm.wbuf[cB*72 + kkl*32 + g*8];
            bf16x8 B0 = *(const bf16x8*)(bb +  0*72);
            bf16x8 B1 = *(const bf16x8*)(bb + 16*72);
            bf16x8 B2 = *(const bf16x8*)(bb + 32*72);
            bf16x8 B3 = *(const bf16x8*)(bb + 48*72);
            accP0 = MFMA(av0, B0, accP0);  accQ0 = MFMA(av1, B0, accQ0);
            accP1 = MFMA(av0, B1, accP1);  accQ1 = MFMA(av1, B1, accQ1);
            accP2 = MFMA(av0, B2, accP2);  accQ2 = MFMA(av1, B2, accQ2);
            accP3 = MFMA(av0, B3, accP3);  accQ3 = MFMA(av1, B3, accQ3);
        }
    }

    // ---- + directions @ w_dir (K=48 pad 64) ----
    pubStage(pfa, pfb, sm.wbuf, tid);                 // wsDir
    loadStage(wsM1, 64, tid, pfa, pfb);               // prefetch M1a
    #pragma unroll
    for (int kk = 0; kk < 2; ++kk){
        int k0 = kk*32 + g*8;
        unsigned int a0w0 = pk2bf(dirv2(sm,px0,py0,pz0,sl0,k0+0), dirv2(sm,px0,py0,pz0,sl0,k0+1));
        unsigned int a0w1 = pk2bf(dirv2(sm,px0,py0,pz0,sl0,k0+2), dirv2(sm,px0,py0,pz0,sl0,k0+3));
        unsigned int a0w2 = pk2bf(dirv2(sm,px0,py0,pz0,sl0,k0+4), dirv2(sm,px0,py0,pz0,sl0,k0+5));
        unsigned int a0w3 = pk2bf(dirv2(sm,px0,py0,pz0,sl0,k0+6), dirv2(sm,px0,py0,pz0,sl0,k0+7));
        bf16x8 av0 = __builtin_bit_cast(bf16x8, (u32x4){a0w0,a0w1,a0w2,a0w3});
        unsigned int a1w0 = pk2bf(dirv2(sm,px1,py1,pz1,sl1,k0+0), dirv2(sm,px1,py1,pz1,sl1,k0+1));
        unsigned int a1w1 = pk2bf(dirv2(sm,px1,py1,pz1,sl1,k0+2), dirv2(sm,px1,py1,pz1,sl1,k0+3));
        unsigned int a1w2 = pk2bf(dirv2(sm,px1,py1,pz1,sl1,k0+4), dirv2(sm,px1,py1,pz1,sl1,k0+5));
        unsigned int a1w3 = pk2bf(dirv2(sm,px1,py1,pz1,sl1,k0+6), dirv2(sm,px1,py1,pz1,sl1,k0+7));
        bf16x8 av1 = __builtin_bit_cast(bf16x8, (u32x4){a1w0,a1w1,a1w2,a1w3});
        const unsigned short* bb = &sm.wbuf[cB*72 + k0];
        bf16x8 B0 = *(const bf16x8*)(bb +  0*72);
        bf16x8 B1 = *(const bf16x8*)(bb + 16*72);
        bf16x8 B2 = *(const bf16x8*)(bb + 32*72);
        bf16x8 B3 = *(const bf16x8*)(bb + 48*72);
        accP0 = MFMA(av0, B0, accP0);  accQ0 = MFMA(av1, B0, accQ0);
        accP1 = MFMA(av0, B1, accP1);  accQ1 = MFMA(av1, B1, accQ1);
        accP2 = MFMA(av0, B2, accP2);  accQ2 = MFMA(av1, B2, accQ2);
        accP3 = MFMA(av0, B3, accP3);  accQ3 = MFMA(av1, B3, accQ3);
    }

    // ---- epilogue: + base + wtype, LayerNorm (rsq), bf16 stores to pairT ----
    #pragma unroll
    for (int t = 0; t < 2; ++t){
        #pragma unroll
        for (int r = 0; r < 4; ++r){
            int slr = 32*wv + 16*t + g*4 + r;
            int ty  = sm.typef[slr];
            float a0 = (t==0 ? accP0[r] : accQ0[r]);
            float a1 = (t==0 ? accP1[r] : accQ1[r]);
            float a2 = (t==0 ? accP2[r] : accQ2[r]);
            float a3 = (t==0 ? accP3[r] : accQ3[r]);
            float v0 = a0 + bs0 + sm.wtypef[ty*PD + cB +  0];
            float v1 = a1 + bs1 + sm.wtypef[ty*PD + cB + 16];
            float v2 = a2 + bs2 + sm.wtypef[ty*PD + cB + 32];
            float v3 = a3 + bs3 + sm.wtypef[ty*PD + cB + 48];
            float ssum = v0+v1+v2+v3;
            ssum += __shfl_xor(ssum,1); ssum += __shfl_xor(ssum,2);
            ssum += __shfl_xor(ssum,4); ssum += __shfl_xor(ssum,8);
            float mu = ssum * (1.0f/64.0f);
            float d0=v0-mu, d1=v1-mu, d2=v2-mu, d3=v3-mu;
            float sq = d0*d0+d1*d1+d2*d2+d3*d3;
            sq += __shfl_xor(sq,1); sq += __shfl_xor(sq,2);
            sq += __shfl_xor(sq,4); sq += __shfl_xor(sq,8);
            float inv = __builtin_amdgcn_rsqf(sq*(1.0f/64.0f) + 1e-5f);
            unsigned short* pr = &sm.pairT[slr*72];
            pr[cB +  0] = f2bfhu(d0*inv*lnS0 + lnO0);
            pr[cB + 16] = f2bfhu(d1*inv*lnS1 + lnO1);
            pr[cB + 32] = f2bfhu(d2*inv*lnS2 + lnO2);
            pr[cB + 48] = f2bfhu(d3*inv*lnS3 + lnO3);
        }
    }

    // ==== MLP1/MLP2 interleaved in k-halves (r15 schedule, prefetched) ====
    f32x4 accO0 = {0.f,0.f,0.f,0.f}, accO1 = accO0, accO2 = accO0, accO3 = accO0;  // tile 0
    f32x4 accN0 = accO0, accN1 = accO0, accN2 = accO0, accN3 = accO0;              // tile 1

    // ---- MLP1 half a (hidden cols 0..63) ----
    f32x4 accH0 = {0.f,0.f,0.f,0.f}, accH1 = accH0, accH2 = accH0, accH3 = accH0;
    f32x4 accI0 = accH0, accI1 = accH0, accI2 = accH0, accI3 = accH0;
    pubStage(pfa, pfb, sm.wbuf, tid);                 // M1a; retires dist, publishes pairT
    loadStage(wsM2, 128, tid, pfa, pfb);              // prefetch M2a
    #pragma unroll
    for (int kk = 0; kk < 2; ++kk){
        bf16x8 a0 = *(const bf16x8*)&sm.pairT[sl0*72 + kk*32 + g*8];
        bf16x8 a1 = *(const bf16x8*)&sm.pairT[sl1*72 + kk*32 + g*8];
        const unsigned short* bb = &sm.wbuf[cB*72 + kk*32 + g*8];
        bf16x8 B0 = *(const bf16x8*)(bb + 0*16*72);
        bf16x8 B1 = *(const bf16x8*)(bb + 1*16*72);
        bf16x8 B2 = *(const bf16x8*)(bb + 2*16*72);
        bf16x8 B3 = *(const bf16x8*)(bb + 3*16*72);
        accH0 = MFMA(a0, B0, accH0);  accI0 = MFMA(a1, B0, accI0);
        accH1 = MFMA(a0, B1, accH1);  accI1 = MFMA(a1, B1, accI1);
        accH2 = MFMA(a0, B2, accH2);  accI2 = MFMA(a1, B2, accI2);
        accH3 = MFMA(a0, B3, accH3);  accI3 = MFMA(a1, B3, accI3);
    }
    #pragma unroll
    for (int r = 0; r < 4; ++r){
        int slr0 = 32*wv + g*4 + r;
        unsigned short* hr0 = &sm.hidT[slr0*72];
        hr0[cB + 0*16] = f2bfhu(gelu_f(accH0[r] + b1a0));
        hr0[cB + 1*16] = f2bfhu(gelu_f(accH1[r] + b1a1));
        hr0[cB + 2*16] = f2bfhu(gelu_f(accH2[r] + b1a2));
        hr0[cB + 3*16] = f2bfhu(gelu_f(accH3[r] + b1a3));
        unsigned short* hr1 = &sm.hidT[(slr0+16)*72];
        hr1[cB + 0*16] = f2bfhu(gelu_f(accI0[r] + b1a0));
        hr1[cB + 1*16] = f2bfhu(gelu_f(accI1[r] + b1a1));
        hr1[cB + 2*16] = f2bfhu(gelu_f(accI2[r] + b1a2));
        hr1[cB + 3*16] = f2bfhu(gelu_f(accI3[r] + b1a3));
    }

    // ---- MLP2 k-half 0 (k = 0..63) ----
    pubStage(pfa, pfb, sm.wbuf, tid);                 // M2a; publishes hidT half a
    loadStage(wsM1 + 64*64, 64, tid, pfa, pfb);       // prefetch M1b
    #pragma unroll
    for (int kkl = 0; kkl < 2; ++kkl){
        bf16x8 a0 = *(const bf16x8*)&sm.hidT[sl0*72 + kkl*32 + g*8];
        bf16x8 a1 = *(const bf16x8*)&sm.hidT[sl1*72 + kkl*32 + g*8];
        const unsigned short* bb = &sm.wbuf[cB*72 + kkl*32 + g*8];
        bf16x8 B0 = *(const bf16x8*)(bb + 0*16*72);
        bf16x8 B1 = *(const bf16x8*)(bb + 1*16*72);
        bf16x8 B2 = *(const bf16x8*)(bb + 2*16*72);
        bf16x8 B3 = *(const bf16x8*)(bb + 3*16*72);
        accO0 = MFMA(a0, B0, accO0);  accN0 = MFMA(a1, B0, accN0);
        accO1 = MFMA(a0, B1, accO1);  accN1 = MFMA(a1, B1, accN1);
        accO2 = MFMA(a0, B2, accO2);  accN2 = MFMA(a1, B2, accN2);
        accO3 = MFMA(a0, B3, accO3);  accN3 = MFMA(a1, B3, accN3);
    }

    // ---- MLP1 half b (hidden cols 64..127) ----
    f32x4 accH4 = {0.f,0.f,0.f,0.f}, accH5 = accH4, accH6 = accH4, accH7 = accH4;
    f32x4 accI4 = accH4, accI5 = accH4, accI6 = accH4, accI7 = accH4;
    pubStage(pfa, pfb, sm.wbuf, tid);                 // M1b; retires hidT-half-a reads
    loadStage(wsM2 + 64, 128, tid, pfa, pfb);         // prefetch M2b
    #pragma unroll
    for (int kk = 0; kk < 2; ++kk){
        bf16x8 a0 = *(const bf16x8*)&sm.pairT[sl0*72 + kk*32 + g*8];
        bf16x8 a1 = *(const bf16x8*)&sm.pairT[sl1*72 + kk*32 + g*8];
        const unsigned short* bb = &sm.wbuf[cB*72 + kk*32 + g*8];
        bf16x8 B0 = *(const bf16x8*)(bb + 0*16*72);
        bf16x8 B1 = *(const bf16x8*)(bb + 1*16*72);
        bf16x8 B2 = *(const bf16x8*)(bb + 2*16*72);
        bf16x8 B3 = *(const bf16x8*)(bb + 3*16*72);
        accH4 = MFMA(a0, B0, accH4);  accI4 = MFMA(a1, B0, accI4);
        accH5 = MFMA(a0, B1, accH5);  accI5 = MFMA(a1, B1, accI5);
        accH6 = MFMA(a0, B2, accH6);  accI6 = MFMA(a1, B2, accI6);
        accH7 = MFMA(a0, B3, accH7);  accI7 = MFMA(a1, B3, accI7);
    }
    #pragma unroll
    for (int r = 0; r < 4; ++r){
        int slr0 = 32*wv + g*4 + r;
        unsigned short* hr0 = &sm.hidT[slr0*72];
        hr0[cB + 0*16] = f2bfhu(gelu_f(accH4[r] + b1b0));
        hr0[cB + 1*16] = f2bfhu(gelu_f(accH5[r] + b1b1));
        hr0[cB + 2*16] = f2bfhu(gelu_f(accH6[r] + b1b2));
        hr0[cB + 3*16] = f2bfhu(gelu_f(accH7[r] + b1b3));
        unsigned short* hr1 = &sm.hidT[(slr0+16)*72];
        hr1[cB + 0*16] = f2bfhu(gelu_f(accI4[r] + b1b0));
        hr1[cB + 1*16] = f2bfhu(gelu_f(accI5[r] + b1b1));
        hr1[cB + 2*16] = f2bfhu(gelu_f(accI6[r] + b1b2));
        hr1[cB + 3*16] = f2bfhu(gelu_f(accI7[r] + b1b3));
    }

    // ---- MLP2 k-half 1 (k = 64..127) ----
    pubStage(pfa, pfb, sm.wbuf, tid);                 // M2b; publishes hidT half b
    #pragma unroll
    for (int kkl = 0; kkl < 2; ++kkl){
        bf16x8 a0 = *(const bf16x8*)&sm.hidT[sl0*72 + kkl*32 + g*8];
        bf16x8 a1 = *(const bf16x8*)&sm.hidT[sl1*72 + kkl*32 + g*8];
        const unsigned short* bb = &sm.wbuf[cB*72 + kkl*32 + g*8];
        bf16x8 B0 = *(const bf16x8*)(bb + 0*16*72);
        bf16x8 B1 = *(const bf16x8*)(bb + 1*16*72);
        bf16x8 B2 = *(const bf16x8*)(bb + 2*16*72);
        bf16x8 B3 = *(const bf16x8*)(bb + 3*16*72);
        accO0 = MFMA(a0, B0, accO0);  accN0 = MFMA(a1, B0, accN0);
        accO1 = MFMA(a0, B1, accO1);  accN1 = MFMA(a1, B1, accN1);
        accO2 = MFMA(a0, B2, accO2);  accN2 = MFMA(a1, B2, accN2);
        accO3 = MFMA(a0, B3, accO3);  accN3 = MFMA(a1, B3, accN3);
    }

    float pooled0 = 0.f, pooled1 = 0.f, pooled2 = 0.f, pooled3 = 0.f;
    #pragma unroll
    for (int r = 0; r < 4; ++r){
        float m0f = sm.maskf[32*wv + g*4 + r];
        float m1f = sm.maskf[32*wv + 16 + g*4 + r];
        pooled0 += m0f * accO0[r] + m1f * accN0[r];
        pooled1 += m0f * accO1[r] + m1f * accN1[r];
        pooled2 += m0f * accO2[r] + m1f * accN2[r];
        pooled3 += m0f * accO3[r] + m1f * accN3[r];
    }

    // ---- reduce pooled: across g-groups (same col), then across waves ----
    pooled0 += __shfl_xor(pooled0,16); pooled0 += __shfl_xor(pooled0,32);
    pooled1 += __shfl_xor(pooled1,16); pooled1 += __shfl_xor(pooled1,32);
    pooled2 += __shfl_xor(pooled2,16); pooled2 += __shfl_xor(pooled2,32);
    pooled3 += __shfl_xor(pooled3,16); pooled3 += __shfl_xor(pooled3,32);
    if (g == 0){
        sm.red[wv*PD + cB +  0] = pooled0;
        sm.red[wv*PD + cB + 16] = pooled1;
        sm.red[wv*PD + cB + 32] = pooled2;
        sm.red[wv*PD + cB + 48] = pooled3;
    }
    __syncthreads();
    if (tid < PD){
        float v = sm.red[tid] + sm.red[PD + tid] + sm.red[2*PD + tid] + sm.red[3*PD + tid];
        float mc = fmaxf(sm.cnt, 1.0f);
        v = (v + sm.cnt * sm.b2v[tid]) / mc;        // adds b2 exactly like ref (0 if cnt==0)
        sm.fin[tid] = sm.gatevv[tid] * v;
    }
    __syncthreads();
    {
        float a = 0.f;
        #pragma unroll 4
        for (int p = 0; p < PD; ++p) a += sm.fin[p] * w_out[p*LD + tid];
        g_out[n*LD + tid] = a;
    }
}

extern "C" void kernel_launch(void* const* d_in, const int* in_sizes, int n_in,
                              void* d_out, int out_size, void* d_ws, size_t ws_size,
                              hipStream_t stream)
{
    (void)in_sizes; (void)n_in; (void)out_size; (void)ws_size;
    const float* g_local   = (const float*)d_in[0];
    const float* g_pos     = (const float*)d_in[1];
    const int*   g_type    = (const int*)  d_in[2];
    const float* g_spos    = (const float*)d_in[3];
    const int*   g_mask    = (const int*)  d_in[4];
    const float* w_points  = (const float*)d_in[5];
    const float* w_type    = (const float*)d_in[6];
    const float* w_local   = (const float*)d_in[7];
    const float* w_dir     = (const float*)d_in[8];
    const float* w_dist    = (const float*)d_in[9];
    const float* ln_scale  = (const float*)d_in[10];
    const float* ln_offset = (const float*)d_in[11];
    const float* w_mlp1    = (const float*)d_in[12];
    const float* b_mlp1    = (const float*)d_in[13];
    const float* w_mlp2    = (const float*)d_in[14];
    const float* b_mlp2    = (const float*)d_in[15];
    const float* w_gate    = (const float*)d_in[16];
    const float* w_out     = (const float*)d_in[17];

    unsigned short* ws = (unsigned short*)d_ws;   // 73728 B

    smol_prep<<<dim3(144), dim3(256), 0, stream>>>(w_dist, w_dir, w_mlp1, w_mlp2, ws);

    smol_fused<<<dim3(NRES), dim3(256), 0, stream>>>(
        g_local, g_pos, g_type, g_spos, g_mask,
        w_points, w_local, w_type, ln_scale, ln_offset,
        b_mlp1, b_mlp2, w_gate, w_out, ws, (float*)d_out);
}

// Round 19
// 122.258 us; speedup vs baseline: 2.3236x; 1.0847x over previous
//
#include <hip/hip_runtime.h>
#include <math.h>

#define NRES 4096
#define SS   128
#define A0C  5
#define ATOT 16
#define LD   256
#define PD   64
#define HD   128

typedef __attribute__((ext_vector_type(8))) short bf16x8;
typedef __attribute__((ext_vector_type(4))) float f32x4;
typedef __attribute__((ext_vector_type(4))) unsigned int u32x4;

__device__ __forceinline__ unsigned short f2bf(float x){
    unsigned int u = __builtin_bit_cast(unsigned int, x);
    unsigned int r = u + 0x7FFFu + ((u >> 16) & 1u);   // RNE to bf16 (prep only)
    return (unsigned short)(r >> 16);
}
__device__ __forceinline__ unsigned short f2bfhu(float x){
    return (unsigned short)((__builtin_bit_cast(unsigned int, x) + 0x8000u) >> 16);
}
__device__ __forceinline__ unsigned int pk2bf(float lo, float hi){
    unsigned int a = __builtin_bit_cast(unsigned int, lo) + 0x8000u;
    unsigned int b = __builtin_bit_cast(unsigned int, hi) + 0x8000u;
    return __builtin_amdgcn_perm(b, a, 0x07060302u);
}
__device__ __forceinline__ float gelu_f(float x){
    float e = __builtin_amdgcn_exp2f(-2.3022082f * x * (1.0f + 0.044715f * x * x));
    return x * __builtin_amdgcn_rcpf(1.0f + e);
}
__device__ __forceinline__ f32x4 MFMA(bf16x8 a, bf16x8 b, f32x4 c){
    return __builtin_amdgcn_mfma_f32_16x16x32_bf16(a, b, c, 0, 0, 0);
}

// ---------------- prep: transpose+convert weights to bf16 in d_ws ----------------
// layout (ushort elements)  [identical to r5..r18 — 73728 B total]:
//   [0)      wsD   [64 n][256 k]   (w_dist^T)
//   [16384)  wsDir [64 n][64 k]    (w_dir^T, k>=48 zero)
//   [20480)  wsM1  [128 n][64 k]   (w_mlp1^T)
//   [28672)  wsM2  [64 n][128 k]   (w_mlp2^T)
__global__ void smol_prep(const float* __restrict__ wdist, const float* __restrict__ wdir,
                          const float* __restrict__ wm1,  const float* __restrict__ wm2,
                          unsigned short* __restrict__ ws)
{
    int i = blockIdx.x * 256 + threadIdx.x;
    if (i < 16384){
        int nn = i >> 8, k = i & 255;
        ws[i] = f2bf(wdist[k*64 + nn]);
    } else if (i < 20480){
        int j = i - 16384; int nn = j >> 6, k = j & 63;
        ws[i] = (k < 48) ? f2bf(wdir[k*64 + nn]) : (unsigned short)0;
    } else if (i < 28672){
        int j = i - 20480; int nn = j >> 6, k = j & 63;
        ws[i] = f2bf(wm1[k*128 + nn]);
    } else if (i < 36864){
        int j = i - 28672; int nn = j >> 7, k = j & 127;
        ws[i] = f2bf(wm2[k*64 + nn]);
    }
}

// ---------------- main fused kernel ----------------
// r19: SWAPPED pair GEMM (weights as A, features as B; identical per-lane
// operand layouts on gfx950 -> operand construction unchanged). Output is
// D[p][s] with s = cB lane-local: LN is a 16-value local sum + 2 shfls, and
// MLP1 A-frags are assembled IN-REGISTER via __shfl (2 shfl + select per
// element; frags reused by both MLP1 halves). pairT LDS DELETED:
// 53.8 KB -> 34.9 KB -> 4 blocks/CU (16 waves/CU, +33% TLP).
struct __align__(16) SMem {
    unsigned short wbuf[64*72];     // 9216 B staged weight slice
    union {
        float  dist[128*17];        // live until dir phase
        unsigned short hidT[128*72];// live in MLP1/MLP2 (after barrier)
    };
    float  loc[LD];
    float  posall3[ATOT*3];
    float  wtypef[7*PD];            // 16B-aligned (prefix sizes all %16==0)
    float  basev[PD];
    float  lnsc[PD], lnof[PD];
    float  b1v[HD];
    float  b2v[PD];
    float  gatevv[PD];
    float  maskf[SS];
    float  red[4*PD];
    float  fin[PD];
    int    typef[SS];
    float  pl[33];
    float  rot[9];
    float  ca3[3];
    float  cnt;
};

__device__ __forceinline__ float dirv2(const SMem& sm, float px, float py, float pz,
                                       int sl, int k){
    int kc = (k < 48) ? k : 47;
    int a = (kc * 21846) >> 16;     // kc/3
    int c = kc - 3*a;
    float pc = (c == 0) ? px : ((c == 1) ? py : pz);
    float e = (pc - sm.posall3[a*3+c]) * __builtin_amdgcn_rcpf(sm.dist[sl*17 + a]);
    return (k < 48) ? e : 0.0f;
}

__device__ __forceinline__ void loadStage(const unsigned short* __restrict__ src, int stride,
                                          int tid, u32x4& a, u32x4& b){
    int r = tid >> 3, s = (tid & 7) * 8;
    a = *(const u32x4*)&src[r*stride + s];
    b = *(const u32x4*)&src[(r+32)*stride + s];
}
__device__ __forceinline__ void pubStage(u32x4 a, u32x4 b, unsigned short* dst, int tid){
    __syncthreads();
    int r = tid >> 3, s = (tid & 7) * 8;
    *(u32x4*)&dst[r*72 + s]      = a;
    *(u32x4*)&dst[(r+32)*72 + s] = b;
    __syncthreads();
}

// RBF feature fragment (unchanged build; now used as the B operand)
#define RBF_FRAG(av, sl) do {                                               \
    float dA_ = sm.dist[(sl)*17 + 2*kk + (g>>1)] * 1.60149654f;             \
    float z0_ = dA_ - (b0c + 0.00000000f);                                  \
    float z1_ = dA_ - (b0c + 1.28119724f);                                  \
    float z2_ = dA_ - (b0c + 2.56239447f);                                  \
    float z3_ = dA_ - (b0c + 3.84359171f);                                  \
    float z4_ = dA_ - (b0c + 5.12478894f);                                  \
    float z5_ = dA_ - (b0c + 6.40598618f);                                  \
    float z6_ = dA_ - (b0c + 7.68718342f);                                  \
    float z7_ = dA_ - (b0c + 8.96838065f);                                  \
    unsigned int w0_ = pk2bf(__builtin_amdgcn_exp2f((-z0_)*z0_),            \
                             __builtin_amdgcn_exp2f((-z1_)*z1_));           \
    unsigned int w1_ = pk2bf(__builtin_amdgcn_exp2f((-z2_)*z2_),            \
                             __builtin_amdgcn_exp2f((-z3_)*z3_));           \
    unsigned int w2_ = pk2bf(__builtin_amdgcn_exp2f((-z4_)*z4_),            \
                             __builtin_amdgcn_exp2f((-z5_)*z5_));           \
    unsigned int w3_ = pk2bf(__builtin_amdgcn_exp2f((-z6_)*z6_),            \
                             __builtin_amdgcn_exp2f((-z7_)*z7_));           \
    av = __builtin_bit_cast(bf16x8, (u32x4){w0_, w1_, w2_, w3_});           \
} while(0)

// Assemble MLP1 A-frag (row s=cB-local, k=32kk+8g+j) from LN'd registers.
// k=32kk+8g+j lives at src lane (2(g&1)+(j>>2))*16+cB, reg ln[2kk+(g>>1)][j&3].
// Lm0 = ln[t][2kk], Lm1 = ln[t][2kk+1].
#define MK_FRAG(F, Lm0, Lm1) do {                                           \
    float a0_ = __shfl(Lm0[0], srcA), b0_ = __shfl(Lm1[0], srcA);           \
    float a1_ = __shfl(Lm0[1], srcA), b1_ = __shfl(Lm1[1], srcA);           \
    float a2_ = __shfl(Lm0[2], srcA), b2_ = __shfl(Lm1[2], srcA);           \
    float a3_ = __shfl(Lm0[3], srcA), b3_ = __shfl(Lm1[3], srcA);           \
    float a4_ = __shfl(Lm0[0], srcB), b4_ = __shfl(Lm1[0], srcB);           \
    float a5_ = __shfl(Lm0[1], srcB), b5_ = __shfl(Lm1[1], srcB);           \
    float a6_ = __shfl(Lm0[2], srcB), b6_ = __shfl(Lm1[2], srcB);           \
    float a7_ = __shfl(Lm0[3], srcB), b7_ = __shfl(Lm1[3], srcB);           \
    float v0_ = hi ? b0_ : a0_;  float v1_ = hi ? b1_ : a1_;                \
    float v2_ = hi ? b2_ : a2_;  float v3_ = hi ? b3_ : a3_;                \
    float v4_ = hi ? b4_ : a4_;  float v5_ = hi ? b5_ : a5_;                \
    float v6_ = hi ? b6_ : a6_;  float v7_ = hi ? b7_ : a7_;                \
    F = __builtin_bit_cast(bf16x8, (u32x4){pk2bf(v0_,v1_), pk2bf(v2_,v3_),  \
                                           pk2bf(v4_,v5_), pk2bf(v6_,v7_)});\
} while(0)

// LN epilogue for one s-tile: acc[m][r] holds pair[s=cB-local][p=16m+4g+r].
#define TILE_LN(L0, L1, L2, L3, A0, A1, A2, A3, tyv) do {                   \
    f32x4 v0_ = A0 + bV0 + *(const f32x4*)&sm.wtypef[(tyv)*PD + pb +  0];   \
    f32x4 v1_ = A1 + bV1 + *(const f32x4*)&sm.wtypef[(tyv)*PD + pb + 16];   \
    f32x4 v2_ = A2 + bV2 + *(const f32x4*)&sm.wtypef[(tyv)*PD + pb + 32];   \
    f32x4 v3_ = A3 + bV3 + *(const f32x4*)&sm.wtypef[(tyv)*PD + pb + 48];   \
    float ss_ = v0_[0]+v0_[1]+v0_[2]+v0_[3] + v1_[0]+v1_[1]+v1_[2]+v1_[3]   \
              + v2_[0]+v2_[1]+v2_[2]+v2_[3] + v3_[0]+v3_[1]+v3_[2]+v3_[3];  \
    ss_ += __shfl_xor(ss_,16); ss_ += __shfl_xor(ss_,32);                   \
    float mu_ = ss_ * (1.0f/64.0f);                                         \
    f32x4 d0_ = v0_ - mu_, d1_ = v1_ - mu_, d2_ = v2_ - mu_, d3_ = v3_ - mu_;\
    float sq_ = d0_[0]*d0_[0]+d0_[1]*d0_[1]+d0_[2]*d0_[2]+d0_[3]*d0_[3]     \
              + d1_[0]*d1_[0]+d1_[1]*d1_[1]+d1_[2]*d1_[2]+d1_[3]*d1_[3]     \
              + d2_[0]*d2_[0]+d2_[1]*d2_[1]+d2_[2]*d2_[2]+d2_[3]*d2_[3]     \
              + d3_[0]*d3_[0]+d3_[1]*d3_[1]+d3_[2]*d3_[2]+d3_[3]*d3_[3];    \
    sq_ += __shfl_xor(sq_,16); sq_ += __shfl_xor(sq_,32);                   \
    float inv_ = __builtin_amdgcn_rsqf(sq_*(1.0f/64.0f) + 1e-5f);           \
    L0 = d0_*inv_*sV0 + oV0;  L1 = d1_*inv_*sV1 + oV1;                      \
    L2 = d2_*inv_*sV2 + oV2;  L3 = d3_*inv_*sV3 + oV3;                      \
} while(0)

__global__ __launch_bounds__(256, 4)
void smol_fused(const float* __restrict__ g_local,
                const float* __restrict__ g_pos,
                const int*   __restrict__ g_type,
                const float* __restrict__ g_spos,
                const int*   __restrict__ g_mask,
                const float* __restrict__ w_points,
                const float* __restrict__ w_local,
                const float* __restrict__ w_type,
                const float* __restrict__ ln_scale,
                const float* __restrict__ ln_offset,
                const float* __restrict__ b_mlp1,
                const float* __restrict__ b_mlp2,
                const float* __restrict__ w_gate,
                const float* __restrict__ w_out,
                const unsigned short* __restrict__ ws,
                float* __restrict__ g_out)
{
    __shared__ SMem sm;
    const int n    = blockIdx.x;
    const int tid  = threadIdx.x;
    const int wv   = tid >> 6;        // wave 0..3 : owns rows 32wv..32wv+31
    const int lane = tid & 63;
    const int cB   = lane & 15;
    const int g    = lane >> 4;       // k-subgroup 0..3
    const int sl0  = 32*wv + cB;      // tile-0 s row (lane-local!)
    const int sl1  = sl0 + 16;        // tile-1 s row

    const unsigned short* wsD   = ws;
    const unsigned short* wsDir = ws + 16384;
    const unsigned short* wsM1  = ws + 20480;
    const unsigned short* wsM2  = ws + 28672;

    // ---------- stage per-n data + small weights ----------
    sm.loc[tid] = g_local[n*LD + tid];
    sm.wtypef[tid] = w_type[tid];
    if (tid < 7*PD - 256) sm.wtypef[256 + tid] = w_type[256 + tid];
    if (tid < PD){ sm.lnsc[tid] = ln_scale[tid]; sm.lnof[tid] = ln_offset[tid]; sm.b2v[tid] = b_mlp2[tid]; }
    if (tid < HD) sm.b1v[tid] = b_mlp1[tid];
    if (tid < SS){ sm.typef[tid] = g_type[n*SS + tid];
                   sm.maskf[tid] = (g_mask[n*SS + tid] != 0) ? 1.0f : 0.0f; }
    if (tid >= 128 && tid < 128 + A0C*3) sm.posall3[tid-128] = g_pos[n*A0C*3 + (tid-128)];
    __syncthreads();

    // ---------- per-n precompute ----------
    if (tid < 33){
        float a = 0.f;
        for (int i = 0; i < LD; ++i) a += sm.loc[i] * w_points[i*33 + tid];
        sm.pl[tid] = a;
    } else if (tid >= 64 && tid < 128){
        int p = tid - 64; float a = 0.f;
        for (int i = 0; i < LD; ++i) a += sm.loc[i] * w_local[i*PD + p];
        sm.basev[p] = a;
    } else if (tid >= 128 && tid < 192){
        int p = tid - 128; float a = 0.f;
        for (int i = 0; i < LD; ++i) a += sm.loc[i] * w_gate[i*PD + p];
        sm.gatevv[p] = gelu_f(a);
    } else if (tid == 255){
        float nx=sm.posall3[0], ny=sm.posall3[1], nz=sm.posall3[2];
        float cax=sm.posall3[3], cay=sm.posall3[4], caz=sm.posall3[5];
        float cx=sm.posall3[6], cy=sm.posall3[7], cz=sm.posall3[8];
        float v1x=cx-cax, v1y=cy-cay, v1z=cz-caz;
        float r = 1.0f/sqrtf(v1x*v1x + v1y*v1y + v1z*v1z + 1e-6f);
        float e1x=v1x*r, e1y=v1y*r, e1z=v1z*r;
        float v2x=nx-cax, v2y=ny-cay, v2z=nz-caz;
        float dp = e1x*v2x + e1y*v2y + e1z*v2z;
        float u2x=v2x-e1x*dp, u2y=v2y-e1y*dp, u2z=v2z-e1z*dp;
        r = 1.0f/sqrtf(u2x*u2x + u2y*u2y + u2z*u2z + 1e-6f);
        float e2x=u2x*r, e2y=u2y*r, e2z=u2z*r;
        float e3x=e1y*e2z-e1z*e2y, e3y=e1z*e2x-e1x*e2z, e3z=e1x*e2y-e1y*e2x;
        sm.rot[0]=e1x; sm.rot[1]=e2x; sm.rot[2]=e3x;
        sm.rot[3]=e1y; sm.rot[4]=e2y; sm.rot[5]=e3y;
        sm.rot[6]=e1z; sm.rot[7]=e2z; sm.rot[8]=e3z;
        sm.ca3[0]=cax; sm.ca3[1]=cay; sm.ca3[2]=caz;
    } else if (tid == 254){
        float c = 0.f;
        for (int s = 0; s < SS; ++s) c += sm.maskf[s];
        sm.cnt = c;
    }
    __syncthreads();
    if (tid < 33){
        int k = tid / 3, i2 = tid - k*3;
        sm.posall3[(A0C + k)*3 + i2] =
            sm.rot[i2*3+0]*sm.pl[k*3+0] + sm.rot[i2*3+1]*sm.pl[k*3+1] +
            sm.rot[i2*3+2]*sm.pl[k*3+2] + sm.ca3[i2];
    }
    __syncthreads();   // posall3 visible to all waves

    // own-row smol coords in REGISTERS
    const float px0 = g_spos[(n*SS + sl0)*3 + 0];
    const float py0 = g_spos[(n*SS + sl0)*3 + 1];
    const float pz0 = g_spos[(n*SS + sl0)*3 + 2];
    const float px1 = g_spos[(n*SS + sl1)*3 + 0];
    const float py1 = g_spos[(n*SS + sl1)*3 + 1];
    const float pz1 = g_spos[(n*SS + sl1)*3 + 2];

    // prefetch slice 0 (wsD k 0..63)
    u32x4 pfa, pfb;
    loadStage(wsD, 256, tid, pfa, pfb);

    // dist for this wave's 32 rows
    #pragma unroll
    for (int aa = 0; aa < 4; ++aa){
        int a = g*4 + aa;
        float ax = sm.posall3[a*3+0], ay = sm.posall3[a*3+1], az = sm.posall3[a*3+2];
        float rx0 = px0-ax, ry0 = py0-ay, rz0 = pz0-az;
        sm.dist[sl0*17 + a] = sqrtf(rx0*rx0 + ry0*ry0 + rz0*rz0 + 1e-6f);
        float rx1 = px1-ax, ry1 = py1-ay, rz1 = pz1-az;
        sm.dist[sl1*17 + a] = sqrtf(rx1*rx1 + ry1*ry1 + rz1*rz1 + 1e-6f);
    }

    const float b0c = (float)((g&1) * 8) * 1.28119724f;
    const float b1a0 = sm.b1v[cB+0*16], b1a1 = sm.b1v[cB+1*16],
                b1a2 = sm.b1v[cB+2*16], b1a3 = sm.b1v[cB+3*16];
    const float b1b0 = sm.b1v[cB+4*16], b1b1 = sm.b1v[cB+5*16],
                b1b2 = sm.b1v[cB+6*16], b1b3 = sm.b1v[cB+7*16];

    // ---- pair GEMM (SWAPPED): accP_m = pair[p=16m+4g+r][s tile0], accQ_m tile1
    f32x4 accP0 = {0.f,0.f,0.f,0.f}, accP1 = accP0, accP2 = accP0, accP3 = accP0;
    f32x4 accQ0 = accP0, accQ1 = accP0, accQ2 = accP0, accQ3 = accP0;

    for (int h = 0; h < 4; ++h){
        pubStage(pfa, pfb, sm.wbuf, tid);
        if (h < 3) loadStage(wsD + (h+1)*64, 256, tid, pfa, pfb);
        else       loadStage(wsDir, 64, tid, pfa, pfb);
        #pragma unroll
        for (int kkl = 0; kkl < 2; ++kkl){
            const int kk = h*2 + kkl;
            bf16x8 av0, av1;
            RBF_FRAG(av0, sl0);
            RBF_FRAG(av1, sl1);
            const unsigned short* bb = &sm.wbuf[cB*72 + kkl*32 + g*8];
            bf16x8 B0 = *(const bf16x8*)(bb +  0*72);
            bf16x8 B1 = *(const bf16x8*)(bb + 16*72);
            bf16x8 B2 = *(const bf16x8*)(bb + 32*72);
            bf16x8 B3 = *(const bf16x8*)(bb + 48*72);
            accP0 = MFMA(B0, av0, accP0);  accQ0 = MFMA(B0, av1, accQ0);
            accP1 = MFMA(B1, av0, accP1);  accQ1 = MFMA(B1, av1, accQ1);
            accP2 = MFMA(B2, av0, accP2);  accQ2 = MFMA(B2, av1, accQ2);
            accP3 = MFMA(B3, av0, accP3);  accQ3 = MFMA(B3, av1, accQ3);
        }
    }

    // ---- + directions @ w_dir (swapped likewise) ----
    pubStage(pfa, pfb, sm.wbuf, tid);                 // wsDir
    loadStage(wsM1, 64, tid, pfa, pfb);               // prefetch M1a
    #pragma unroll
    for (int kk = 0; kk < 2; ++kk){
        int k0 = kk*32 + g*8;
        unsigned int a0w0 = pk2bf(dirv2(sm,px0,py0,pz0,sl0,k0+0), dirv2(sm,px0,py0,pz0,sl0,k0+1));
        unsigned int a0w1 = pk2bf(dirv2(sm,px0,py0,pz0,sl0,k0+2), dirv2(sm,px0,py0,pz0,sl0,k0+3));
        unsigned int a0w2 = pk2bf(dirv2(sm,px0,py0,pz0,sl0,k0+4), dirv2(sm,px0,py0,pz0,sl0,k0+5));
        unsigned int a0w3 = pk2bf(dirv2(sm,px0,py0,pz0,sl0,k0+6), dirv2(sm,px0,py0,pz0,sl0,k0+7));
        bf16x8 av0 = __builtin_bit_cast(bf16x8, (u32x4){a0w0,a0w1,a0w2,a0w3});
        unsigned int a1w0 = pk2bf(dirv2(sm,px1,py1,pz1,sl1,k0+0), dirv2(sm,px1,py1,pz1,sl1,k0+1));
        unsigned int a1w1 = pk2bf(dirv2(sm,px1,py1,pz1,sl1,k0+2), dirv2(sm,px1,py1,pz1,sl1,k0+3));
        unsigned int a1w2 = pk2bf(dirv2(sm,px1,py1,pz1,sl1,k0+4), dirv2(sm,px1,py1,pz1,sl1,k0+5));
        unsigned int a1w3 = pk2bf(dirv2(sm,px1,py1,pz1,sl1,k0+6), dirv2(sm,px1,py1,pz1,sl1,k0+7));
        bf16x8 av1 = __builtin_bit_cast(bf16x8, (u32x4){a1w0,a1w1,a1w2,a1w3});
        const unsigned short* bb = &sm.wbuf[cB*72 + k0];
        bf16x8 B0 = *(const bf16x8*)(bb +  0*72);
        bf16x8 B1 = *(const bf16x8*)(bb + 16*72);
        bf16x8 B2 = *(const bf16x8*)(bb + 32*72);
        bf16x8 B3 = *(const bf16x8*)(bb + 48*72);
        accP0 = MFMA(B0, av0, accP0);  accQ0 = MFMA(B0, av1, accQ0);
        accP1 = MFMA(B1, av0, accP1);  accQ1 = MFMA(B1, av1, accQ1);
        accP2 = MFMA(B2, av0, accP2);  accQ2 = MFMA(B2, av1, accQ2);
        accP3 = MFMA(B3, av0, accP3);  accQ3 = MFMA(B3, av1, accQ3);
    }

    // ---- epilogue: LN per s-row (lane-local), frags assembled in-register ----
    const int pb  = 4*g;
    const bool hi = (g >> 1);
    const int srcA = ((g&1) << 5) + cB;   // lane of g' = 2(g&1)
    const int srcB = srcA + 16;           // lane of g' = 2(g&1)+1

    const f32x4 bV0 = *(const f32x4*)&sm.basev[pb +  0];
    const f32x4 bV1 = *(const f32x4*)&sm.basev[pb + 16];
    const f32x4 bV2 = *(const f32x4*)&sm.basev[pb + 32];
    const f32x4 bV3 = *(const f32x4*)&sm.basev[pb + 48];
    const f32x4 sV0 = *(const f32x4*)&sm.lnsc[pb +  0];
    const f32x4 sV1 = *(const f32x4*)&sm.lnsc[pb + 16];
    const f32x4 sV2 = *(const f32x4*)&sm.lnsc[pb + 32];
    const f32x4 sV3 = *(const f32x4*)&sm.lnsc[pb + 48];
    const f32x4 oV0 = *(const f32x4*)&sm.lnof[pb +  0];
    const f32x4 oV1 = *(const f32x4*)&sm.lnof[pb + 16];
    const f32x4 oV2 = *(const f32x4*)&sm.lnof[pb + 32];
    const f32x4 oV3 = *(const f32x4*)&sm.lnof[pb + 48];

    bf16x8 F00, F01, F10, F11;   // A-frags: F[t][kk]
    {
        int ty0 = sm.typef[sl0];
        f32x4 L0, L1, L2, L3;
        TILE_LN(L0, L1, L2, L3, accP0, accP1, accP2, accP3, ty0);
        MK_FRAG(F00, L0, L1);
        MK_FRAG(F01, L2, L3);
    }
    {
        int ty1 = sm.typef[sl1];
        f32x4 L0, L1, L2, L3;
        TILE_LN(L0, L1, L2, L3, accQ0, accQ1, accQ2, accQ3, ty1);
        MK_FRAG(F10, L0, L1);
        MK_FRAG(F11, L2, L3);
    }

    // ==== MLP1/MLP2 interleaved in k-halves; A-frags from registers ====
    f32x4 accO0 = {0.f,0.f,0.f,0.f}, accO1 = accO0, accO2 = accO0, accO3 = accO0;
    f32x4 accN0 = accO0, accN1 = accO0, accN2 = accO0, accN3 = accO0;

    // ---- MLP1 half a (hidden cols 0..63) ----
    f32x4 accH0 = {0.f,0.f,0.f,0.f}, accH1 = accH0, accH2 = accH0, accH3 = accH0;
    f32x4 accI0 = accH0, accI1 = accH0, accI2 = accH0, accI3 = accH0;
    pubStage(pfa, pfb, sm.wbuf, tid);                 // M1a; retires dist (hidT union safe)
    loadStage(wsM2, 128, tid, pfa, pfb);              // prefetch M2a
    #pragma unroll
    for (int kk = 0; kk < 2; ++kk){
        bf16x8 a0 = kk ? F01 : F00;
        bf16x8 a1 = kk ? F11 : F10;
        const unsigned short* bb = &sm.wbuf[cB*72 + kk*32 + g*8];
        bf16x8 B0 = *(const bf16x8*)(bb + 0*16*72);
        bf16x8 B1 = *(const bf16x8*)(bb + 1*16*72);
        bf16x8 B2 = *(const bf16x8*)(bb + 2*16*72);
        bf16x8 B3 = *(const bf16x8*)(bb + 3*16*72);
        accH0 = MFMA(a0, B0, accH0);  accI0 = MFMA(a1, B0, accI0);
        accH1 = MFMA(a0, B1, accH1);  accI1 = MFMA(a1, B1, accI1);
        accH2 = MFMA(a0, B2, accH2);  accI2 = MFMA(a1, B2, accI2);
        accH3 = MFMA(a0, B3, accH3);  accI3 = MFMA(a1, B3, accI3);
    }
    #pragma unroll
    for (int r = 0; r < 4; ++r){
        int slr0 = 32*wv + g*4 + r;
        unsigned short* hr0 = &sm.hidT[slr0*72];
        hr0[cB + 0*16] = f2bfhu(gelu_f(accH0[r] + b1a0));
        hr0[cB + 1*16] = f2bfhu(gelu_f(accH1[r] + b1a1));
        hr0[cB + 2*16] = f2bfhu(gelu_f(accH2[r] + b1a2));
        hr0[cB + 3*16] = f2bfhu(gelu_f(accH3[r] + b1a3));
        unsigned short* hr1 = &sm.hidT[(slr0+16)*72];
        hr1[cB + 0*16] = f2bfhu(gelu_f(accI0[r] + b1a0));
        hr1[cB + 1*16] = f2bfhu(gelu_f(accI1[r] + b1a1));
        hr1[cB + 2*16] = f2bfhu(gelu_f(accI2[r] + b1a2));
        hr1[cB + 3*16] = f2bfhu(gelu_f(accI3[r] + b1a3));
    }

    // ---- MLP2 k-half 0 (k = 0..63) ----
    pubStage(pfa, pfb, sm.wbuf, tid);                 // M2a; publishes hidT half a
    loadStage(wsM1 + 64*64, 64, tid, pfa, pfb);       // prefetch M1b
    #pragma unroll
    for (int kkl = 0; kkl < 2; ++kkl){
        bf16x8 a0 = *(const bf16x8*)&sm.hidT[sl0*72 + kkl*32 + g*8];
        bf16x8 a1 = *(const bf16x8*)&sm.hidT[sl1*72 + kkl*32 + g*8];
        const unsigned short* bb = &sm.wbuf[cB*72 + kkl*32 + g*8];
        bf16x8 B0 = *(const bf16x8*)(bb + 0*16*72);
        bf16x8 B1 = *(const bf16x8*)(bb + 1*16*72);
        bf16x8 B2 = *(const bf16x8*)(bb + 2*16*72);
        bf16x8 B3 = *(const bf16x8*)(bb + 3*16*72);
        accO0 = MFMA(a0, B0, accO0);  accN0 = MFMA(a1, B0, accN0);
        accO1 = MFMA(a0, B1, accO1);  accN1 = MFMA(a1, B1, accN1);
        accO2 = MFMA(a0, B2, accO2);  accN2 = MFMA(a1, B2, accN2);
        accO3 = MFMA(a0, B3, accO3);  accN3 = MFMA(a1, B3, accN3);
    }

    // ---- MLP1 half b (hidden cols 64..127), reusing the SAME frags ----
    f32x4 accH4 = {0.f,0.f,0.f,0.f}, accH5 = accH4, accH6 = accH4, accH7 = accH4;
    f32x4 accI4 = accH4, accI5 = accH4, accI6 = accH4, accI7 = accH4;
    pubStage(pfa, pfb, sm.wbuf, tid);                 // M1b; retires hidT-half-a reads
    loadStage(wsM2 + 64, 128, tid, pfa, pfb);         // prefetch M2b
    #pragma unroll
    for (int kk = 0; kk < 2; ++kk){
        bf16x8 a0 = kk ? F01 : F00;
        bf16x8 a1 = kk ? F11 : F10;
        const unsigned short* bb = &sm.wbuf[cB*72 + kk*32 + g*8];
        bf16x8 B0 = *(const bf16x8*)(bb + 0*16*72);
        bf16x8 B1 = *(const bf16x8*)(bb + 1*16*72);
        bf16x8 B2 = *(const bf16x8*)(bb + 2*16*72);
        bf16x8 B3 = *(const bf16x8*)(bb + 3*16*72);
        accH4 = MFMA(a0, B0, accH4);  accI4 = MFMA(a1, B0, accI4);
        accH5 = MFMA(a0, B1, accH5);  accI5 = MFMA(a1, B1, accI5);
        accH6 = MFMA(a0, B2, accH6);  accI6 = MFMA(a1, B2, accI6);
        accH7 = MFMA(a0, B3, accH7);  accI7 = MFMA(a1, B3, accI7);
    }
    #pragma unroll
    for (int r = 0; r < 4; ++r){
        int slr0 = 32*wv + g*4 + r;
        unsigned short* hr0 = &sm.hidT[slr0*72];
        hr0[cB + 0*16] = f2bfhu(gelu_f(accH4[r] + b1b0));
        hr0[cB + 1*16] = f2bfhu(gelu_f(accH5[r] + b1b1));
        hr0[cB + 2*16] = f2bfhu(gelu_f(accH6[r] + b1b2));
        hr0[cB + 3*16] = f2bfhu(gelu_f(accH7[r] + b1b3));
        unsigned short* hr1 = &sm.hidT[(slr0+16)*72];
        hr1[cB + 0*16] = f2bfhu(gelu_f(accI4[r] + b1b0));
        hr1[cB + 1*16] = f2bfhu(gelu_f(accI5[r] + b1b1));
        hr1[cB + 2*16] = f2bfhu(gelu_f(accI6[r] + b1b2));
        hr1[cB + 3*16] = f2bfhu(gelu_f(accI7[r] + b1b3));
    }

    // ---- MLP2 k-half 1 (k = 64..127) ----
    pubStage(pfa, pfb, sm.wbuf, tid);                 // M2b; publishes hidT half b
    #pragma unroll
    for (int kkl = 0; kkl < 2; ++kkl){
        bf16x8 a0 = *(const bf16x8*)&sm.hidT[sl0*72 + kkl*32 + g*8];
        bf16x8 a1 = *(const bf16x8*)&sm.hidT[sl1*72 + kkl*32 + g*8];
        const unsigned short* bb = &sm.wbuf[cB*72 + kkl*32 + g*8];
        bf16x8 B0 = *(const bf16x8*)(bb + 0*16*72);
        bf16x8 B1 = *(const bf16x8*)(bb + 1*16*72);
        bf16x8 B2 = *(const bf16x8*)(bb + 2*16*72);
        bf16x8 B3 = *(const bf16x8*)(bb + 3*16*72);
        accO0 = MFMA(a0, B0, accO0);  accN0 = MFMA(a1, B0, accN0);
        accO1 = MFMA(a0, B1, accO1);  accN1 = MFMA(a1, B1, accN1);
        accO2 = MFMA(a0, B2, accO2);  accN2 = MFMA(a1, B2, accN2);
        accO3 = MFMA(a0, B3, accO3);  accN3 = MFMA(a1, B3, accN3);
    }

    float pooled0 = 0.f, pooled1 = 0.f, pooled2 = 0.f, pooled3 = 0.f;
    #pragma unroll
    for (int r = 0; r < 4; ++r){
        float m0f = sm.maskf[32*wv + g*4 + r];
        float m1f = sm.maskf[32*wv + 16 + g*4 + r];
        pooled0 += m0f * accO0[r] + m1f * accN0[r];
        pooled1 += m0f * accO1[r] + m1f * accN1[r];
        pooled2 += m0f * accO2[r] + m1f * accN2[r];
        pooled3 += m0f * accO3[r] + m1f * accN3[r];
    }

    // ---- reduce pooled: across g-groups, then across waves ----
    pooled0 += __shfl_xor(pooled0,16); pooled0 += __shfl_xor(pooled0,32);
    pooled1 += __shfl_xor(pooled1,16); pooled1 += __shfl_xor(pooled1,32);
    pooled2 += __shfl_xor(pooled2,16); pooled2 += __shfl_xor(pooled2,32);
    pooled3 += __shfl_xor(pooled3,16); pooled3 += __shfl_xor(pooled3,32);
    if (g == 0){
        sm.red[wv*PD + cB +  0] = pooled0;
        sm.red[wv*PD + cB + 16] = pooled1;
        sm.red[wv*PD + cB + 32] = pooled2;
        sm.red[wv*PD + cB + 48] = pooled3;
    }
    __syncthreads();
    if (tid < PD){
        float v = sm.red[tid] + sm.red[PD + tid] + sm.red[2*PD + tid] + sm.red[3*PD + tid];
        float mc = fmaxf(sm.cnt, 1.0f);
        v = (v + sm.cnt * sm.b2v[tid]) / mc;
        sm.fin[tid] = sm.gatevv[tid] * v;
    }
    __syncthreads();
    {
        float a = 0.f;
        #pragma unroll 4
        for (int p = 0; p < PD; ++p) a += sm.fin[p] * w_out[p*LD + tid];
        g_out[n*LD + tid] = a;
    }
}

extern "C" void kernel_launch(void* const* d_in, const int* in_sizes, int n_in,
                              void* d_out, int out_size, void* d_ws, size_t ws_size,
                              hipStream_t stream)
{
    (void)in_sizes; (void)n_in; (void)out_size; (void)ws_size;
    const float* g_local   = (const float*)d_in[0];
    const float* g_pos     = (const float*)d_in[1];
    const int*   g_type    = (const int*)  d_in[2];
    const float* g_spos    = (const float*)d_in[3];
    const int*   g_mask    = (const int*)  d_in[4];
    const float* w_points  = (const float*)d_in[5];
    const float* w_type    = (const float*)d_in[6];
    const float* w_local   = (const float*)d_in[7];
    const float* w_dir     = (const float*)d_in[8];
    const float* w_dist    = (const float*)d_in[9];
    const float* ln_scale  = (const float*)d_in[10];
    const float* ln_offset = (const float*)d_in[11];
    const float* w_mlp1    = (const float*)d_in[12];
    const float* b_mlp1    = (const float*)d_in[13];
    const float* w_mlp2    = (const float*)d_in[14];
    const float* b_mlp2    = (const float*)d_in[15];
    const float* w_gate    = (const float*)d_in[16];
    const float* w_out     = (const float*)d_in[17];

    unsigned short* ws = (unsigned short*)d_ws;   // 73728 B

    smol_prep<<<dim3(144), dim3(256), 0, stream>>>(w_dist, w_dir, w_mlp1, w_mlp2, ws);

    smol_fused<<<dim3(NRES), dim3(256), 0, stream>>>(
        g_local, g_pos, g_type, g_spos, g_mask,
        w_points, w_local, w_type, ln_scale, ln_offset,
        b_mlp1, b_mlp2, w_gate, w_out, ws, (float*)d_out);
}